// Round 8
// baseline (1005.287 us; speedup 1.0000x reference)
//
#include <hip/hip_runtime.h>
#include <hip/hip_bf16.h>

// Problem constants
#define NTOT 65536      // B*N
#define KNN  20
#define KROW 104        // bf16 kf row stride (67 dims + pad) = 208 bytes

typedef __attribute__((ext_vector_type(4))) float f32x4;
typedef __attribute__((ext_vector_type(8))) short s16x8;

// ws layout (bytes): kfB bf16[65536][104] | normB f32[65536] | nbr i32
#define WS_NORM 13631488
#define WS_NBR  13893632

// ---- k_knn LDS map (bytes) ----
// buf: 64 rows x 257 dwords (256 columns + 1 pad) = 65792
// col = qLocal*8 + kq  (qLocal 0..31 within block, kq = key eighth 0..7)
// total 70016 B -> 2 blocks/CU co-resident (grid 512 = 2 blocks/CU)
#define ROWS 64
#define CSTR 257
#define OFF_MG   65792      // unsigned mg[32*32] = 4096
#define OFF_TAUG 69888      // unsigned tauG[32] = 128
#define KNN_SMEM 70016
#define THRESH 48           // compact when cntR > THRESH; check EVERY group:
                            // 48+16 = 64 <= ROWS (exact bound)

__device__ __forceinline__ unsigned short f2bf_rne(float v){
  unsigned u = __float_as_uint(v);
  return (unsigned short)((u + 0x7FFFu + ((u >> 16) & 1u)) >> 16);
}

// ---------------------------------------------------------------------------
// k_prep: kf = [s(16), R^T v(48), pos(3), -0.5|k|^2 as bf16 hi/lo] -> bf16
// rows (stride 104) + f32 norm. Dims 67/68 carry the norm so the d2 MFMA
// needs no separate ksq load (query side patches 1.0 into those dims).
// ---------------------------------------------------------------------------
__global__ __launch_bounds__(256) void k_prep(const float* __restrict__ x,
        const float* __restrict__ pos, const float* __restrict__ lfr,
        unsigned short* __restrict__ kfB, float* __restrict__ normB){
  int n = blockIdx.x * 256 + threadIdx.x;
  const float* xr = x + n * 64;
  float R[9];
  #pragma unroll
  for (int j = 0; j < 9; j++) R[j] = lfr[n * 9 + j];
  float c[67];
  #pragma unroll
  for (int i = 0; i < 16; i++) c[i] = xr[i];
  #pragma unroll
  for (int k = 0; k < 16; k++){
    float v0 = xr[16 + 3*k], v1 = xr[17 + 3*k], v2 = xr[18 + 3*k];
    #pragma unroll
    for (int a = 0; a < 3; a++)
      c[16 + 3*k + a] = R[a] * v0 + R[3 + a] * v1 + R[6 + a] * v2;  // R^T v
  }
  #pragma unroll
  for (int a = 0; a < 3; a++) c[64 + a] = pos[n * 3 + a];
  float sq = 0.f;
  #pragma unroll
  for (int d = 0; d < 67; d++) sq += c[d] * c[d];
  __attribute__((aligned(16))) unsigned short row[KROW];
  #pragma unroll
  for (int d = 0; d < 67; d++) row[d] = f2bf_rne(c[d]);
  #pragma unroll
  for (int d = 67; d < KROW; d++) row[d] = 0;
  // -0.5*|k|^2 split into bf16 hi/lo at dims 67,68
  {
    float h = -0.5f * sq;
    unsigned short hi = f2bf_rne(h);
    float hif = __uint_as_float(((unsigned)hi) << 16);
    row[67] = hi;
    row[68] = f2bf_rne(h - hif);
  }
  uint4* dst = (uint4*)(kfB + (size_t)n * KROW);
  const uint4* s4 = (const uint4*)row;
  #pragma unroll
  for (int i = 0; i < 13; i++) dst[i] = s4[i];
  normB[n] = sq;
}

// ---------------------------------------------------------------------------
// col_compact64: exact top-32 (unique 32-bit packed values) of one column
// with cn (<=64) entries -- single register per lane, one ballot per round.
// 32-round ballot binary search for the 32nd smallest, ballot-prefix rewrite.
// Wave-local, no barriers.
// ---------------------------------------------------------------------------
__device__ __forceinline__ unsigned col_compact64(unsigned* buf,
    int col, int cn, int lane){
  unsigned e0 = (lane < cn) ? buf[lane * CSTR + col] : 0xFFFFFFFFu;
  unsigned T = 0;
  #pragma unroll 1
  for (int b = 31; b >= 0; --b){
    unsigned cand = T | (1u << b);
    if (__popcll(__ballot(e0 < cand)) <= 31) T = cand;
  }
  unsigned long long m0 = __ballot(e0 <= T);
  unsigned long long ltm = (1ull << lane) - 1ull;
  if (e0 <= T) buf[__popcll(m0 & ltm) * CSTR + col] = e0;
  return T;
}

// ---------------------------------------------------------------------------
// k_knn: barrier-free wave-autonomous scan. 512 blocks x 1024 thr (16 waves)
// = 2 blocks/CU (70KB LDS, no min-waves bound -> natural ~56 VGPR, no spill)
// -> 8 waves/SIMD. Wave (wq 0..1, kq 0..7): 16 queries x 2048 keys (128
// groups -- HALF the per-wave serial work of the 256-block layout). Keys
// direct from global (L2-resident, norm folded into key row). Counts in
// quad-uniform registers; shared monotone tau via atomicMin over 8 kq waves.
// ---------------------------------------------------------------------------
__global__ __launch_bounds__(1024, 4) void k_knn(
    const unsigned short* __restrict__ kfB, const float* __restrict__ normB,
    const float* __restrict__ x, const float* __restrict__ pos,
    const float* __restrict__ lfr, int* __restrict__ nbr){
  __shared__ __attribute__((aligned(16))) char smem[KNN_SMEM];
  unsigned* buf = (unsigned*)smem;
  unsigned* mg = (unsigned*)(smem + OFF_MG);
  unsigned* tauG = (unsigned*)(smem + OFF_TAUG);

  int tid = threadIdx.x;
  int blk = blockIdx.x;            // 0..511
  int b = blk & 3;                 // batch
  int qloc0 = (blk >> 2) << 5;     // query block within batch: 0..4064
  int bbase = b << 14;

  if (tid < 32) tauG[tid] = 0x7F7FC000u;   // huge float (not NaN)

  int lane = tid & 63;
  int wv = tid >> 6;               // 0..15
  int wq = wv >> 3;                // query sub-group 0..1
  int kq = wv & 7;                 // key eighth 0..7
  int l15 = lane & 15, quad = lane >> 4;
  int colB = (wq << 7) + kq;       // col = colB + quad*32 + r*8

  // A fragments: wave's 16 queries; patch dims 67/68 -> 1.0 (norm-fold trick)
  int qloc = qloc0 + (wq << 4);
  s16x8 af[3];
  {
    int nodeA = bbase + ((qloc + l15) << 2);
    const unsigned short* ap = kfB + (size_t)nodeA * KROW + quad * 8;
    af[0] = *(const s16x8*)(ap);
    af[1] = *(const s16x8*)(ap + 32);
    af[2] = *(const s16x8*)(ap + 64);
  }
  if (quad == 0){ af[2][3] = (short)0x3F80; af[2][4] = (short)0x3F80; }
  float qsq[4];
  #pragma unroll
  for (int r = 0; r < 4; r++)
    qsq[r] = normB[bbase + ((qloc + (quad << 2) + r) << 2)];

  float tauR[4] = {3.0e38f, 3.0e38f, 3.0e38f, 3.0e38f};
  int cntR[4] = {32, 32, 32, 32};  // seeds occupy rows 0..31

  // per-lane key stream base: key (kq*2048 + g*16 + l15), bytes quad*16..+48
  const unsigned short* kp = kfB
      + (size_t)(bbase + (kq << 11) + l15) * KROW + quad * 8;

  __syncthreads();   // tauG init visible

  s16x8 cA[3], cB[3];
  #define LOADK(dst) do { \
      dst[0] = *(const s16x8*)(kp); \
      dst[1] = *(const s16x8*)(kp + 32); \
      dst[2] = *(const s16x8*)(kp + 64); \
      kp += 16 * KROW; } while (0)

  auto comp = [&](const s16x8 bf[3], float d2v[4]){
    f32x4 acc = (f32x4){0.f, 0.f, 0.f, 0.f};
    acc = __builtin_amdgcn_mfma_f32_16x16x32_bf16(af[0], bf[0], acc, 0, 0, 0);
    acc = __builtin_amdgcn_mfma_f32_16x16x32_bf16(af[1], bf[1], acc, 0, 0, 0);
    acc = __builtin_amdgcn_mfma_f32_16x16x32_bf16(af[2], bf[2], acc, 0, 0, 0);
    #pragma unroll
    for (int r = 0; r < 4; r++)                      // d2 = |q|^2 - 2*acc
      d2v[r] = fmaxf(fmaf(-2.f, acc[r], qsq[r]), 0.f);
  };

  auto seed = [&](const float d2v[4], int g){
    int kidx = (kq << 11) + (g << 4) + l15;
    #pragma unroll
    for (int r = 0; r < 4; r++){
      unsigned pk = ((__float_as_uint(d2v[r]) + 0x2000u) & 0xFFFFC000u) | (unsigned)kidx;
      buf[((g << 4) + l15) * CSTR + colB + (quad << 5) + (r << 3)] = pk;
    }
  };

  auto process = [&](const float d2v[4], int g){
    bool p[4];
    #pragma unroll
    for (int r = 0; r < 4; r++) p[r] = d2v[r] < tauR[r];
    if (__any(p[0] | p[1] | p[2] | p[3])){
      int kidx = (kq << 11) + (g << 4) + l15;
      #pragma unroll
      for (int r = 0; r < 4; r++){
        unsigned long long m = __ballot(p[r]);
        if (m){
          int lo = (int)((m >> (quad << 4)) & 0xFFFFull);
          if (lo){
            int colr = colB + (quad << 5) + (r << 3);
            int pre = __popc(lo & ((1 << l15) - 1));
            if (p[r]){
              unsigned pk = ((__float_as_uint(d2v[r]) + 0x2000u) & 0xFFFFC000u) | (unsigned)kidx;
              buf[(cntR[r] + pre) * CSTR + colr] = pk;
            }
            cntR[r] += __popc(lo);      // quad-uniform update, no atomics
          }
        }
      }
    }
  };

  auto check_compact = [&](int limit){
    #pragma unroll
    for (int r = 0; r < 4; r++){
      unsigned long long mr = __ballot(cntR[r] > limit);
      while (mr){
        int ldr = __ffsll((unsigned long long)mr) - 1;
        int qd = ldr >> 4;
        mr &= ~(0xFFFFull << (qd << 4));
        int col = colB + (qd << 5) + (r << 3);
        int cn = __shfl(cntR[r], qd << 4, 64);
        unsigned T = col_compact64(buf, col, cn, lane);
        if (quad == qd) cntR[r] = 32;
        if (lane == 0) atomicMin(&tauG[(wq << 4) + (qd << 2) + r], T);
      }
    }
  };

  auto tau_refresh = [&](){
    uint4 tg = *(const uint4*)&tauG[(wq << 4) + (quad << 2)];
    tauR[0] = __uint_as_float(tg.x & 0xFFFFC000u);
    tauR[1] = __uint_as_float(tg.y & 0xFFFFC000u);
    tauR[2] = __uint_as_float(tg.z & 0xFFFFC000u);
    tauR[3] = __uint_as_float(tg.w & 0xFFFFC000u);
  };

  // ---- prologue: seed groups 0,1; tau-seed from the 32 initial entries ----
  {
    float d2v[4];
    LOADK(cA);               // g0
    LOADK(cB);               // g1
    comp(cA, d2v); seed(d2v, 0);
    LOADK(cA);               // prefetch g2
    comp(cB, d2v); seed(d2v, 1);
    LOADK(cB);               // prefetch g3
    check_compact(31);       // every column: T = max of its 32 seeds -> tau
    tau_refresh();
  }

  // ---- main scan: 2 groups/iter, compact-check every group ----
  #pragma unroll 1
  for (int g = 2; g < 128; g += 2){
    float d2v[4];
    comp(cA, d2v);
    LOADK(cA);               // prefetch g+2 (tail overruns into valid ws)
    process(d2v, g);
    check_compact(THRESH);
    tau_refresh();
    comp(cB, d2v);
    LOADK(cB);               // prefetch g+3
    process(d2v, g + 1);
    check_compact(THRESH);
    tau_refresh();
  }

  // ---- final per-column exact top-32 (all columns end at exactly 32) ----
  check_compact(32);
  __syncthreads();

  // ---- per-query merge of 8 columns (8x32 = 256 fixed) -> top-32 into mg ----
  #pragma unroll 1
  for (int s = 0; s < 2; s++){
    int q = (wv << 1) + s;           // 0..31
    unsigned e[4];
    #pragma unroll
    for (int j = 0; j < 4; j++)
      e[j] = buf[(lane & 31) * CSTR + (q << 3) + (j << 1) + (lane >> 5)];
    unsigned T = 0;
    #pragma unroll 1
    for (int bb = 31; bb >= 0; --bb){
      unsigned cand = T | (1u << bb);
      int c = 0;
      #pragma unroll
      for (int j = 0; j < 4; j++) c += __popcll(__ballot(e[j] < cand));
      if (c <= 31) T = cand;
    }
    unsigned long long m[4];
    #pragma unroll
    for (int j = 0; j < 4; j++) m[j] = __ballot(e[j] <= T);
    unsigned long long ltm = (1ull << lane) - 1ull;
    int base = 0;
    #pragma unroll
    for (int j = 0; j < 4; j++){
      int p = base + __popcll(m[j] & ltm);
      if ((e[j] <= T) && (p < 32)) mg[(q << 5) + p] = e[j];
      base += __popcll(m[j]);
    }
  }
  __syncthreads();

  // ---- fp64 exact rerank of 32 candidates/query (overlays buf region) ----
  double* qkf = (double*)(smem);            // 32*67*8 = 17152
  double* rrD = (double*)(smem + 17152);    // 32*32*8 = 8192
  int*    rrI = (int*)(smem + 25344);       // 32*32*4 = 4096

  {
    int t32 = tid & 31, q = tid >> 5;       // q 0..31
    int node = bbase + ((qloc0 + q) << 2);
    const float* xr = x + node * 64;
    for (int dd = t32; dd < 67; dd += 32){
      double val;
      if (dd < 16) val = (double)xr[dd];
      else if (dd < 64){
        int r = dd - 16; int k = r / 3; int a = r - 3 * k;
        val = (double)lfr[node*9 + a]     * (double)xr[16 + 3*k]
            + (double)lfr[node*9 + 3 + a] * (double)xr[17 + 3*k]
            + (double)lfr[node*9 + 6 + a] * (double)xr[18 + 3*k];
      } else val = (double)pos[node*3 + (dd - 64)];
      qkf[q * 67 + dd] = val;
    }
  }
  __syncthreads();
  {
    int j = tid & 31, q = tid >> 5;         // one candidate per thread
    int idx = (int)(mg[(q << 5) + j] & 0x3FFFu);
    int node = bbase + idx;
    const float* xr = x + node * 64;
    double R[9];
    #pragma unroll
    for (int t = 0; t < 9; t++) R[t] = (double)lfr[node * 9 + t];
    double d2 = 0.0;
    #pragma unroll
    for (int dd = 0; dd < 16; dd++){ double t = (double)xr[dd] - qkf[q*67 + dd]; d2 += t * t; }
    #pragma unroll
    for (int k = 0; k < 16; k++){
      double v0 = xr[16 + 3*k], v1 = xr[17 + 3*k], v2 = xr[18 + 3*k];
      #pragma unroll
      for (int a = 0; a < 3; a++){
        double val = R[a] * v0 + R[3 + a] * v1 + R[6 + a] * v2;
        double t = val - qkf[q*67 + 16 + 3*k + a]; d2 += t * t;
      }
    }
    #pragma unroll
    for (int a = 0; a < 3; a++){ double t = (double)pos[node*3 + a] - qkf[q*67 + 64 + a]; d2 += t * t; }
    rrD[q * 32 + j] = d2; rrI[q * 32 + j] = idx;
  }
  __syncthreads();
  if (tid < 32){
    int qq = tid;
    int qid = (b << 12) + qloc0 + qq;
    #pragma unroll 1
    for (int s = 0; s < KNN; s++){
      double best = rrD[qq * 32 + s]; int bi = s;
      for (int t = s + 1; t < 32; t++){
        double v = rrD[qq * 32 + t]; if (v < best){ best = v; bi = t; }
      }
      double tv = rrD[qq * 32 + bi]; rrD[qq * 32 + bi] = rrD[qq * 32 + s]; rrD[qq * 32 + s] = tv;
      int ti = rrI[qq * 32 + bi]; rrI[qq * 32 + bi] = rrI[qq * 32 + s]; rrI[qq * 32 + s] = ti;
      nbr[qid * KNN + s] = bbase + rrI[qq * 32 + s];
    }
  }
}

// ---------------------------------------------------------------------------
// k_mlp (MFMA rewrite): 8 queries/block = 160 edge-rows (10 m-tiles), 512 thr
// (8 waves, wave wv owns 16 output cols). bf16 MFMA both layers, fp32 acc.
// LDS k-blocked layouts [k/32][row][32] (16B-aligned b128 frags, 2-way banks).
// Max-over-20-edges fully in registers via compile-time query-boundary masks.
// ---------------------------------------------------------------------------
#define M_X   0         // xs f32[160][68] = 43520 ; later Wt2 bf16[4][128][32]
#define M_H   43520     // hB bf16[4][160][32] = 40960
#define M_A1  84480     // a1B bf16[4][160][32] = 40960 (early: nbrL/xdL/lfL overlay)
#define M_W   125440    // Wt1 bf16[4][128][32] = 32768
#define M_B1  158208    // b1 f32[128]
#define M_B2  158720    // b2 f32[128]
#define M_SZ  159232

__global__ __launch_bounds__(512) void k_mlp(const float* __restrict__ x,
    const float* __restrict__ lfr, const int* __restrict__ nbr,
    const float* __restrict__ W1, const float* __restrict__ b1,
    const float* __restrict__ W2, const float* __restrict__ b2,
    float* __restrict__ out){
  __shared__ __attribute__((aligned(16))) char smem[M_SZ];
  float* xsF = (float*)(smem + M_X);
  unsigned short* hB = (unsigned short*)(smem + M_H);
  unsigned short* a1B = (unsigned short*)(smem + M_A1);
  unsigned short* wt1 = (unsigned short*)(smem + M_W);
  unsigned short* wt2 = (unsigned short*)(smem + M_X);
  float* b1L = (float*)(smem + M_B1);
  float* b2L = (float*)(smem + M_B2);
  int*   nbrL = (int*)(smem + M_A1);            // overlay (dead before a1 writes)
  float* xdL  = (float*)(smem + M_A1 + 640);    // 8x64 f32
  float* lfL  = (float*)(smem + M_A1 + 2688);   // 8x9 f32

  int tid = threadIdx.x;
  int qid0 = blockIdx.x * 8;
  int lane = tid & 63, wv = tid >> 6;
  int l15 = lane & 15, quad = lane >> 4;

  // ---- init loads ----
  if (tid < 160) nbrL[tid] = nbr[qid0 * 20 + tid];
  {
    int q = tid >> 6, d = tid & 63;
    int qid = qid0 + q;
    int node = ((qid >> 12) << 14) + ((qid & 4095) << 2);
    xdL[q * 64 + d] = x[node * 64 + d];
  }
  if (tid < 72){
    int q = tid / 9, j = tid - 9 * q;
    int qid = qid0 + q;
    int node = ((qid >> 12) << 14) + ((qid & 4095) << 2);
    lfL[q * 9 + j] = lfr[node * 9 + j];
  }
  if (tid < 128){ b1L[tid] = b1[tid]; b2L[tid] = b2[tid]; }
  __syncthreads();

  // ---- gather x_src into xs (160 rows x 64 f32, stride 68) ----
  {
    int f4 = tid & 15;
    #pragma unroll
    for (int p = 0; p < 5; p++){
      int e = (tid >> 4) + (p << 5);
      float4 v = *(const float4*)&x[(size_t)nbrL[e] * 64 + (f4 << 2)];
      *(float4*)&xsF[e * 68 + (f4 << 2)] = v;
    }
  }
  __syncthreads();

  // ---- build h bf16 into hB [d>>5][e][d&31] ----
  {
    int d = tid & 127, eo = tid >> 7;   // eo 0..3
    int cls, kk = 0, aa = 0;
    if (d < 64) cls = 0;
    else { int dd = d - 64;
      if (dd < 16) cls = 1;
      else { cls = 2; int r = dd - 16; kk = (r * 21846) >> 16; aa = r - 3 * kk; } }
    int hoff = ((d >> 5) * 160) * 32 + (d & 31);
    #pragma unroll 4
    for (int p = 0; p < 40; p++){
      int e = eo + (p << 2);
      int q = (e * 3277) >> 16;       // e/20 for e<160
      float v;
      if (cls == 0) v = xdL[q * 64 + d];
      else if (cls == 1) v = xsF[e * 68 + (d - 64)] - xdL[q * 64 + (d - 64)];
      else {
        int base = 16 + 3 * kk;
        float u0 = xsF[e * 68 + base]     - xdL[q * 64 + base];
        float u1 = xsF[e * 68 + base + 1] - xdL[q * 64 + base + 1];
        float u2 = xsF[e * 68 + base + 2] - xdL[q * 64 + base + 2];
        v = lfL[q * 9 + aa * 3] * u0 + lfL[q * 9 + aa * 3 + 1] * u1 + lfL[q * 9 + aa * 3 + 2] * u2;
      }
      hB[hoff + e * 32] = f2bf_rne(v);
    }
  }
  __syncthreads();   // hB done; xs/xdL/lfL/nbrL dead

  // ---- stage Wt1 -> M_W, Wt2 -> M_X  (layout [k>>5][n][32], value W[k][n]) ----
  #pragma unroll 4
  for (int i = tid; i < 16384; i += 512){
    int k = i >> 7, n = i & 127;
    int a = ((k >> 5) * 128 + n) * 32 + (k & 31);
    wt1[a] = f2bf_rne(W1[i]);
    wt2[a] = f2bf_rne(W2[i]);
  }
  __syncthreads();   // weights visible

  // ---- layer 1: a1 = relu(h @ W1 + b1) ----
  {
    s16x8 bfr[4];
    #pragma unroll
    for (int ks = 0; ks < 4; ks++)
      bfr[ks] = *(const s16x8*)(wt1 + ((ks * 128 + (wv << 4) + l15) * 32 + (quad << 3)));
    float b1v = b1L[(wv << 4) + l15];
    int colhi = wv >> 1, collo = ((wv & 1) << 4) + l15;
    #pragma unroll
    for (int mt = 0; mt < 10; mt++){
      f32x4 acc = (f32x4){0.f, 0.f, 0.f, 0.f};
      #pragma unroll
      for (int ks = 0; ks < 4; ks++){
        s16x8 af = *(const s16x8*)(hB + ((ks * 160 + (mt << 4) + l15) * 32 + (quad << 3)));
        acc = __builtin_amdgcn_mfma_f32_16x16x32_bf16(af, bfr[ks], acc, 0, 0, 0);
      }
      #pragma unroll
      for (int r = 0; r < 4; r++){
        float v = fmaxf(acc[r] + b1v, 0.f);
        int row = (mt << 4) + (quad << 2) + r;
        a1B[(colhi * 160 + row) * 32 + collo] = f2bf_rne(v);
      }
    }
  }
  __syncthreads();   // a1 complete

  // ---- layer 2 + max over edges (registers only) ----
  {
    s16x8 bfr[4];
    #pragma unroll
    for (int ks = 0; ks < 4; ks++)
      bfr[ks] = *(const s16x8*)(wt2 + ((ks * 128 + (wv << 4) + l15) * 32 + (quad << 3)));
    float mxv[8];
    #pragma unroll
    for (int q = 0; q < 8; q++) mxv[q] = -3.0e38f;
    const int QA[10]  = {0,0,1,2,3,4,4,5,6,7};
    const int CUT[10] = {16,4,8,12,16,16,4,8,12,16};
    #pragma unroll
    for (int mt = 0; mt < 10; mt++){
      f32x4 acc = (f32x4){0.f, 0.f, 0.f, 0.f};
      #pragma unroll
      for (int ks = 0; ks < 4; ks++){
        s16x8 af = *(const s16x8*)(a1B + ((ks * 160 + (mt << 4) + l15) * 32 + (quad << 3)));
        acc = __builtin_amdgcn_mfma_f32_16x16x32_bf16(af, bfr[ks], acc, 0, 0, 0);
      }
      int qa = QA[mt], cut = CUT[mt];
      if (cut >= 16){
        #pragma unroll
        for (int r = 0; r < 4; r++) mxv[qa] = fmaxf(mxv[qa], acc[r]);
      } else {
        #pragma unroll
        for (int r = 0; r < 4; r++){
          int lr = (quad << 2) + r;
          bool toA = lr < cut;
          mxv[qa]     = fmaxf(mxv[qa],     toA ? acc[r] : -3.0e38f);
          mxv[qa + 1] = fmaxf(mxv[qa + 1], toA ? -3.0e38f : acc[r]);
        }
      }
    }
    // combine across quads (rows) -- all lanes end with full per-col max
    #pragma unroll
    for (int q = 0; q < 8; q++){
      float v = mxv[q];
      v = fmaxf(v, __shfl_xor(v, 16, 64));
      v = fmaxf(v, __shfl_xor(v, 32, 64));
      mxv[q] = v;
    }
    if (quad == 0){
      int col = (wv << 4) + l15;
      float b2v = b2L[col];
      #pragma unroll
      for (int q = 0; q < 8; q++)
        out[(size_t)(qid0 + q) * 128 + col] = mxv[q] + b2v;
    }
  }
}

// ---------------------------------------------------------------------------
// k_tail: pos[idx], batch[idx], lframes[idx] as fp32 at flat offsets.
// ---------------------------------------------------------------------------
__global__ __launch_bounds__(256) void k_tail(const float* __restrict__ pos,
    const float* __restrict__ lfr, float* __restrict__ out){
  int q = blockIdx.x * 256 + threadIdx.x;   // 0..16383
  int b = q >> 12;
  int node = (b << 14) + ((q & 4095) << 2);
  float* o_pos = out + 2097152;    // 16384*128
  float* o_bat = out + 2146304;    // + 16384*3
  float* o_lf  = out + 2162688;    // + 16384
  #pragma unroll
  for (int j = 0; j < 3; j++) o_pos[q * 3 + j] = pos[node * 3 + j];
  o_bat[q] = (float)b;
  #pragma unroll
  for (int j = 0; j < 9; j++) o_lf[q * 9 + j] = lfr[node * 9 + j];
}

extern "C" void kernel_launch(void* const* d_in, const int* in_sizes, int n_in,
                              void* d_out, int out_size, void* d_ws, size_t ws_size,
                              hipStream_t stream){
  const float* x   = (const float*)d_in[0];
  const float* pos = (const float*)d_in[1];
  const float* lfr = (const float*)d_in[2];
  // d_in[3] = batch (recomputed analytically)
  const float* W1  = (const float*)d_in[4];
  const float* b1  = (const float*)d_in[5];
  const float* W2  = (const float*)d_in[6];
  const float* b2  = (const float*)d_in[7];

  unsigned short* kfB = (unsigned short*)d_ws;
  float* normB = (float*)((char*)d_ws + WS_NORM);
  int*   nbr   = (int*)((char*)d_ws + WS_NBR);
  float* out = (float*)d_out;

  hipLaunchKernelGGL(k_prep, dim3(256),  dim3(256),  0, stream, x, pos, lfr, kfB, normB);
  hipLaunchKernelGGL(k_knn,  dim3(512),  dim3(1024), 0, stream, kfB, normB, x, pos, lfr, nbr);
  hipLaunchKernelGGL(k_mlp,  dim3(2048), dim3(512),  0, stream, x, lfr, nbr, W1, b1, W2, b2, out);
  hipLaunchKernelGGL(k_tail, dim3(64),   dim3(256),  0, stream, pos, lfr, out);
}

// Round 9
// 993.742 us; speedup vs baseline: 1.0116x; 1.0116x over previous
//
#include <hip/hip_runtime.h>
#include <hip/hip_bf16.h>

// Problem constants
#define NTOT 65536      // B*N
#define KNN  20
#define KROW 104        // bf16 kf row stride (67 dims + pad) = 208 bytes

typedef __attribute__((ext_vector_type(4))) float f32x4;
typedef __attribute__((ext_vector_type(8))) short s16x8;

// ws layout (bytes): kfB bf16[65536][104] | normB f32[65536] | nbr i32
#define WS_NORM 13631488
#define WS_NBR  13893632

// ---- k_knn LDS map (bytes) ----
// buf: 64 rows x 129 dwords (128 columns + 1 pad) = 33024 -> 4 blocks/CU
// col = qLocal*8 + kq  (qLocal 0..15 within block, kq = key eighth 0..7)
#define ROWS 64
#define CSTR 129
#define OFF_MG   33024      // unsigned mg[16*32] = 2048
#define OFF_TAUG 35072      // unsigned tauG[16] = 64
#define KNN_SMEM 35136
#define THRESH 48           // compact when cntR > THRESH; check EVERY group:
                            // 48+16 = 64 <= ROWS (exact bound)

__device__ __forceinline__ unsigned short f2bf_rne(float v){
  unsigned u = __float_as_uint(v);
  return (unsigned short)((u + 0x7FFFu + ((u >> 16) & 1u)) >> 16);
}

// ---------------------------------------------------------------------------
// k_prep: kf = [s(16), R^T v(48), pos(3), -0.5|k|^2 as bf16 hi/lo] -> bf16
// rows (stride 104) + f32 norm. Dims 67/68 carry the norm so the d2 MFMA
// needs no separate ksq load (query side patches 1.0 into those dims).
// ---------------------------------------------------------------------------
__global__ __launch_bounds__(256) void k_prep(const float* __restrict__ x,
        const float* __restrict__ pos, const float* __restrict__ lfr,
        unsigned short* __restrict__ kfB, float* __restrict__ normB){
  int n = blockIdx.x * 256 + threadIdx.x;
  const float* xr = x + n * 64;
  float R[9];
  #pragma unroll
  for (int j = 0; j < 9; j++) R[j] = lfr[n * 9 + j];
  float c[67];
  #pragma unroll
  for (int i = 0; i < 16; i++) c[i] = xr[i];
  #pragma unroll
  for (int k = 0; k < 16; k++){
    float v0 = xr[16 + 3*k], v1 = xr[17 + 3*k], v2 = xr[18 + 3*k];
    #pragma unroll
    for (int a = 0; a < 3; a++)
      c[16 + 3*k + a] = R[a] * v0 + R[3 + a] * v1 + R[6 + a] * v2;  // R^T v
  }
  #pragma unroll
  for (int a = 0; a < 3; a++) c[64 + a] = pos[n * 3 + a];
  float sq = 0.f;
  #pragma unroll
  for (int d = 0; d < 67; d++) sq += c[d] * c[d];
  __attribute__((aligned(16))) unsigned short row[KROW];
  #pragma unroll
  for (int d = 0; d < 67; d++) row[d] = f2bf_rne(c[d]);
  #pragma unroll
  for (int d = 67; d < KROW; d++) row[d] = 0;
  // -0.5*|k|^2 split into bf16 hi/lo at dims 67,68
  {
    float h = -0.5f * sq;
    unsigned short hi = f2bf_rne(h);
    float hif = __uint_as_float(((unsigned)hi) << 16);
    row[67] = hi;
    row[68] = f2bf_rne(h - hif);
  }
  uint4* dst = (uint4*)(kfB + (size_t)n * KROW);
  const uint4* s4 = (const uint4*)row;
  #pragma unroll
  for (int i = 0; i < 13; i++) dst[i] = s4[i];
  normB[n] = sq;
}

// ---------------------------------------------------------------------------
// col_compact64: exact top-32 (unique 32-bit packed values) of one column
// with cn (<=64) entries -- single register per lane, one ballot per round.
// 32-round ballot binary search for the 32nd smallest, ballot-prefix rewrite.
// Wave-local, no barriers.
// ---------------------------------------------------------------------------
__device__ __forceinline__ unsigned col_compact64(unsigned* buf,
    int col, int cn, int lane){
  unsigned e0 = (lane < cn) ? buf[lane * CSTR + col] : 0xFFFFFFFFu;
  unsigned T = 0;
  #pragma unroll 1
  for (int b = 31; b >= 0; --b){
    unsigned cand = T | (1u << b);
    if (__popcll(__ballot(e0 < cand)) <= 31) T = cand;
  }
  unsigned long long m0 = __ballot(e0 <= T);
  unsigned long long ltm = (1ull << lane) - 1ull;
  if (e0 <= T) buf[__popcll(m0 & ltm) * CSTR + col] = e0;
  return T;
}

// ---------------------------------------------------------------------------
// k_knn: barrier-free wave-autonomous scan. 1024 blocks x 512 thr (8 waves)
// = 4 blocks/CU (35KB LDS, ~56 VGPR) -> 32 waves/CU of TLP from independent
// NORMAL-sized workgroups (16-wave blocks never co-schedule; 8-wave do).
// Block: 16 queries shared by all waves; wave kq scans keys [kq*2048,
// (kq+1)*2048) = 128 groups. Keys direct from global (L2-resident, norm
// folded into key row). Counts in quad-uniform registers; shared monotone
// tau per query via atomicMin over the 8 kq waves.
// ---------------------------------------------------------------------------
__global__ __launch_bounds__(512, 4) void k_knn(
    const unsigned short* __restrict__ kfB, const float* __restrict__ normB,
    const float* __restrict__ x, const float* __restrict__ pos,
    const float* __restrict__ lfr, int* __restrict__ nbr){
  __shared__ __attribute__((aligned(16))) char smem[KNN_SMEM];
  unsigned* buf = (unsigned*)smem;
  unsigned* mg = (unsigned*)(smem + OFF_MG);
  unsigned* tauG = (unsigned*)(smem + OFF_TAUG);

  int tid = threadIdx.x;
  int blk = blockIdx.x;            // 0..1023
  int b = blk & 3;                 // batch
  int qloc0 = (blk >> 2) << 4;     // query block within batch: 0..4080
  int bbase = b << 14;

  if (tid < 16) tauG[tid] = 0x7F7FC000u;   // huge float (not NaN)

  int lane = tid & 63;
  int kq = tid >> 6;               // wave id = key eighth 0..7
  int l15 = lane & 15, quad = lane >> 4;

  // A fragments: block's 16 queries; patch dims 67/68 -> 1.0 (norm-fold)
  s16x8 af[3];
  {
    int nodeA = bbase + ((qloc0 + l15) << 2);
    const unsigned short* ap = kfB + (size_t)nodeA * KROW + quad * 8;
    af[0] = *(const s16x8*)(ap);
    af[1] = *(const s16x8*)(ap + 32);
    af[2] = *(const s16x8*)(ap + 64);
  }
  if (quad == 0){ af[2][3] = (short)0x3F80; af[2][4] = (short)0x3F80; }
  float qsq[4];
  #pragma unroll
  for (int r = 0; r < 4; r++)
    qsq[r] = normB[bbase + ((qloc0 + (quad << 2) + r) << 2)];

  float tauR[4] = {3.0e38f, 3.0e38f, 3.0e38f, 3.0e38f};
  int cntR[4] = {32, 32, 32, 32};  // seeds occupy rows 0..31

  // per-lane key stream base: key (kq*2048 + g*16 + l15), bytes quad*16..+48
  const unsigned short* kp = kfB
      + (size_t)(bbase + (kq << 11) + l15) * KROW + quad * 8;

  __syncthreads();   // tauG init visible

  s16x8 cA[3], cB[3];
  #define LOADK(dst) do { \
      dst[0] = *(const s16x8*)(kp); \
      dst[1] = *(const s16x8*)(kp + 32); \
      dst[2] = *(const s16x8*)(kp + 64); \
      kp += 16 * KROW; } while (0)

  auto comp = [&](const s16x8 bf[3], float d2v[4]){
    f32x4 acc = (f32x4){0.f, 0.f, 0.f, 0.f};
    acc = __builtin_amdgcn_mfma_f32_16x16x32_bf16(af[0], bf[0], acc, 0, 0, 0);
    acc = __builtin_amdgcn_mfma_f32_16x16x32_bf16(af[1], bf[1], acc, 0, 0, 0);
    acc = __builtin_amdgcn_mfma_f32_16x16x32_bf16(af[2], bf[2], acc, 0, 0, 0);
    #pragma unroll
    for (int r = 0; r < 4; r++)                      // d2 = |q|^2 - 2*acc
      d2v[r] = fmaxf(fmaf(-2.f, acc[r], qsq[r]), 0.f);
  };

  auto seed = [&](const float d2v[4], int g){
    int kidx = (kq << 11) + (g << 4) + l15;
    #pragma unroll
    for (int r = 0; r < 4; r++){
      unsigned pk = ((__float_as_uint(d2v[r]) + 0x2000u) & 0xFFFFC000u) | (unsigned)kidx;
      buf[((g << 4) + l15) * CSTR + kq + (quad << 5) + (r << 3)] = pk;
    }
  };

  auto process = [&](const float d2v[4], int g){
    bool p[4];
    #pragma unroll
    for (int r = 0; r < 4; r++) p[r] = d2v[r] < tauR[r];
    if (__any(p[0] | p[1] | p[2] | p[3])){
      int kidx = (kq << 11) + (g << 4) + l15;
      #pragma unroll
      for (int r = 0; r < 4; r++){
        unsigned long long m = __ballot(p[r]);
        if (m){
          int lo = (int)((m >> (quad << 4)) & 0xFFFFull);
          if (lo){
            int colr = kq + (quad << 5) + (r << 3);
            int pre = __popc(lo & ((1 << l15) - 1));
            if (p[r]){
              unsigned pk = ((__float_as_uint(d2v[r]) + 0x2000u) & 0xFFFFC000u) | (unsigned)kidx;
              buf[(cntR[r] + pre) * CSTR + colr] = pk;
            }
            cntR[r] += __popc(lo);      // quad-uniform update, no atomics
          }
        }
      }
    }
  };

  auto check_compact = [&](int limit){
    #pragma unroll
    for (int r = 0; r < 4; r++){
      unsigned long long mr = __ballot(cntR[r] > limit);
      while (mr){
        int ldr = __ffsll((unsigned long long)mr) - 1;
        int qd = ldr >> 4;
        mr &= ~(0xFFFFull << (qd << 4));
        int col = kq + (qd << 5) + (r << 3);
        int cn = __shfl(cntR[r], qd << 4, 64);
        unsigned T = col_compact64(buf, col, cn, lane);
        if (quad == qd) cntR[r] = 32;
        if (lane == 0) atomicMin(&tauG[(qd << 2) + r], T);
      }
    }
  };

  auto tau_refresh = [&](){
    uint4 tg = *(const uint4*)&tauG[(quad << 2)];
    tauR[0] = __uint_as_float(tg.x & 0xFFFFC000u);
    tauR[1] = __uint_as_float(tg.y & 0xFFFFC000u);
    tauR[2] = __uint_as_float(tg.z & 0xFFFFC000u);
    tauR[3] = __uint_as_float(tg.w & 0xFFFFC000u);
  };

  // ---- prologue: seed groups 0,1; tau-seed from the 32 initial entries ----
  {
    float d2v[4];
    LOADK(cA);               // g0
    LOADK(cB);               // g1
    comp(cA, d2v); seed(d2v, 0);
    LOADK(cA);               // prefetch g2
    comp(cB, d2v); seed(d2v, 1);
    LOADK(cB);               // prefetch g3
    check_compact(31);       // every column: T = max of its 32 seeds -> tau
    tau_refresh();
  }

  // ---- main scan: 2 groups/iter, compact-check every group ----
  #pragma unroll 1
  for (int g = 2; g < 128; g += 2){
    float d2v[4];
    comp(cA, d2v);
    LOADK(cA);               // prefetch g+2 (tail overruns into valid ws)
    process(d2v, g);
    check_compact(THRESH);
    tau_refresh();
    comp(cB, d2v);
    LOADK(cB);               // prefetch g+3
    process(d2v, g + 1);
    check_compact(THRESH);
    tau_refresh();
  }

  // ---- final per-column exact top-32 (all columns end at exactly 32) ----
  check_compact(32);
  __syncthreads();

  // ---- per-query merge of 8 columns (8x32 = 256 fixed) -> top-32 into mg ----
  #pragma unroll 1
  for (int s = 0; s < 2; s++){
    int q = (kq << 1) + s;           // 0..15
    unsigned e[4];
    #pragma unroll
    for (int j = 0; j < 4; j++)
      e[j] = buf[(lane & 31) * CSTR + (q << 3) + (j << 1) + (lane >> 5)];
    unsigned T = 0;
    #pragma unroll 1
    for (int bb = 31; bb >= 0; --bb){
      unsigned cand = T | (1u << bb);
      int c = 0;
      #pragma unroll
      for (int j = 0; j < 4; j++) c += __popcll(__ballot(e[j] < cand));
      if (c <= 31) T = cand;
    }
    unsigned long long m[4];
    #pragma unroll
    for (int j = 0; j < 4; j++) m[j] = __ballot(e[j] <= T);
    unsigned long long ltm = (1ull << lane) - 1ull;
    int base = 0;
    #pragma unroll
    for (int j = 0; j < 4; j++){
      int p = base + __popcll(m[j] & ltm);
      if ((e[j] <= T) && (p < 32)) mg[(q << 5) + p] = e[j];
      base += __popcll(m[j]);
    }
  }
  __syncthreads();

  // ---- fp64 exact rerank of 32 candidates/query (overlays buf region) ----
  double* qkf = (double*)(smem);            // 16*67*8 = 8576
  double* rrD = (double*)(smem + 8576);     // 16*32*8 = 4096
  int*    rrI = (int*)(smem + 12672);       // 16*32*4 = 2048

  {
    int t32 = tid & 31, q = tid >> 5;       // q 0..15
    int node = bbase + ((qloc0 + q) << 2);
    const float* xr = x + node * 64;
    for (int dd = t32; dd < 67; dd += 32){
      double val;
      if (dd < 16) val = (double)xr[dd];
      else if (dd < 64){
        int r = dd - 16; int k = r / 3; int a = r - 3 * k;
        val = (double)lfr[node*9 + a]     * (double)xr[16 + 3*k]
            + (double)lfr[node*9 + 3 + a] * (double)xr[17 + 3*k]
            + (double)lfr[node*9 + 6 + a] * (double)xr[18 + 3*k];
      } else val = (double)pos[node*3 + (dd - 64)];
      qkf[q * 67 + dd] = val;
    }
  }
  __syncthreads();
  {
    int j = tid & 31, q = tid >> 5;         // one candidate per thread
    int idx = (int)(mg[(q << 5) + j] & 0x3FFFu);
    int node = bbase + idx;
    const float* xr = x + node * 64;
    double R[9];
    #pragma unroll
    for (int t = 0; t < 9; t++) R[t] = (double)lfr[node * 9 + t];
    double d2 = 0.0;
    #pragma unroll
    for (int dd = 0; dd < 16; dd++){ double t = (double)xr[dd] - qkf[q*67 + dd]; d2 += t * t; }
    #pragma unroll
    for (int k = 0; k < 16; k++){
      double v0 = xr[16 + 3*k], v1 = xr[17 + 3*k], v2 = xr[18 + 3*k];
      #pragma unroll
      for (int a = 0; a < 3; a++){
        double val = R[a] * v0 + R[3 + a] * v1 + R[6 + a] * v2;
        double t = val - qkf[q*67 + 16 + 3*k + a]; d2 += t * t;
      }
    }
    #pragma unroll
    for (int a = 0; a < 3; a++){ double t = (double)pos[node*3 + a] - qkf[q*67 + 64 + a]; d2 += t * t; }
    rrD[q * 32 + j] = d2; rrI[q * 32 + j] = idx;
  }
  __syncthreads();
  if (tid < 16){
    int qq = tid;
    int qid = (b << 12) + qloc0 + qq;
    #pragma unroll 1
    for (int s = 0; s < KNN; s++){
      double best = rrD[qq * 32 + s]; int bi = s;
      for (int t = s + 1; t < 32; t++){
        double v = rrD[qq * 32 + t]; if (v < best){ best = v; bi = t; }
      }
      double tv = rrD[qq * 32 + bi]; rrD[qq * 32 + bi] = rrD[qq * 32 + s]; rrD[qq * 32 + s] = tv;
      int ti = rrI[qq * 32 + bi]; rrI[qq * 32 + bi] = rrI[qq * 32 + s]; rrI[qq * 32 + s] = ti;
      nbr[qid * KNN + s] = bbase + rrI[qq * 32 + s];
    }
  }
}

// ---------------------------------------------------------------------------
// k_mlp (MFMA rewrite): 8 queries/block = 160 edge-rows (10 m-tiles), 512 thr
// (8 waves, wave wv owns 16 output cols). bf16 MFMA both layers, fp32 acc.
// LDS k-blocked layouts [k/32][row][32] (16B-aligned b128 frags, 2-way banks).
// Max-over-20-edges fully in registers via compile-time query-boundary masks.
// ---------------------------------------------------------------------------
#define M_X   0         // xs f32[160][68] = 43520 ; later Wt2 bf16[4][128][32]
#define M_H   43520     // hB bf16[4][160][32] = 40960
#define M_A1  84480     // a1B bf16[4][160][32] = 40960 (early: nbrL/xdL/lfL overlay)
#define M_W   125440    // Wt1 bf16[4][128][32] = 32768
#define M_B1  158208    // b1 f32[128]
#define M_B2  158720    // b2 f32[128]
#define M_SZ  159232

__global__ __launch_bounds__(512) void k_mlp(const float* __restrict__ x,
    const float* __restrict__ lfr, const int* __restrict__ nbr,
    const float* __restrict__ W1, const float* __restrict__ b1,
    const float* __restrict__ W2, const float* __restrict__ b2,
    float* __restrict__ out){
  __shared__ __attribute__((aligned(16))) char smem[M_SZ];
  float* xsF = (float*)(smem + M_X);
  unsigned short* hB = (unsigned short*)(smem + M_H);
  unsigned short* a1B = (unsigned short*)(smem + M_A1);
  unsigned short* wt1 = (unsigned short*)(smem + M_W);
  unsigned short* wt2 = (unsigned short*)(smem + M_X);
  float* b1L = (float*)(smem + M_B1);
  float* b2L = (float*)(smem + M_B2);
  int*   nbrL = (int*)(smem + M_A1);            // overlay (dead before a1 writes)
  float* xdL  = (float*)(smem + M_A1 + 640);    // 8x64 f32
  float* lfL  = (float*)(smem + M_A1 + 2688);   // 8x9 f32

  int tid = threadIdx.x;
  int qid0 = blockIdx.x * 8;
  int lane = tid & 63, wv = tid >> 6;
  int l15 = lane & 15, quad = lane >> 4;

  // ---- init loads ----
  if (tid < 160) nbrL[tid] = nbr[qid0 * 20 + tid];
  {
    int q = tid >> 6, d = tid & 63;
    int qid = qid0 + q;
    int node = ((qid >> 12) << 14) + ((qid & 4095) << 2);
    xdL[q * 64 + d] = x[node * 64 + d];
  }
  if (tid < 72){
    int q = tid / 9, j = tid - 9 * q;
    int qid = qid0 + q;
    int node = ((qid >> 12) << 14) + ((qid & 4095) << 2);
    lfL[q * 9 + j] = lfr[node * 9 + j];
  }
  if (tid < 128){ b1L[tid] = b1[tid]; b2L[tid] = b2[tid]; }
  __syncthreads();

  // ---- gather x_src into xs (160 rows x 64 f32, stride 68) ----
  {
    int f4 = tid & 15;
    #pragma unroll
    for (int p = 0; p < 5; p++){
      int e = (tid >> 4) + (p << 5);
      float4 v = *(const float4*)&x[(size_t)nbrL[e] * 64 + (f4 << 2)];
      *(float4*)&xsF[e * 68 + (f4 << 2)] = v;
    }
  }
  __syncthreads();

  // ---- build h bf16 into hB [d>>5][e][d&31] ----
  {
    int d = tid & 127, eo = tid >> 7;   // eo 0..3
    int cls, kk = 0, aa = 0;
    if (d < 64) cls = 0;
    else { int dd = d - 64;
      if (dd < 16) cls = 1;
      else { cls = 2; int r = dd - 16; kk = (r * 21846) >> 16; aa = r - 3 * kk; } }
    int hoff = ((d >> 5) * 160) * 32 + (d & 31);
    #pragma unroll 4
    for (int p = 0; p < 40; p++){
      int e = eo + (p << 2);
      int q = (e * 3277) >> 16;       // e/20 for e<160
      float v;
      if (cls == 0) v = xdL[q * 64 + d];
      else if (cls == 1) v = xsF[e * 68 + (d - 64)] - xdL[q * 64 + (d - 64)];
      else {
        int base = 16 + 3 * kk;
        float u0 = xsF[e * 68 + base]     - xdL[q * 64 + base];
        float u1 = xsF[e * 68 + base + 1] - xdL[q * 64 + base + 1];
        float u2 = xsF[e * 68 + base + 2] - xdL[q * 64 + base + 2];
        v = lfL[q * 9 + aa * 3] * u0 + lfL[q * 9 + aa * 3 + 1] * u1 + lfL[q * 9 + aa * 3 + 2] * u2;
      }
      hB[hoff + e * 32] = f2bf_rne(v);
    }
  }
  __syncthreads();   // hB done; xs/xdL/lfL/nbrL dead

  // ---- stage Wt1 -> M_W, Wt2 -> M_X  (layout [k>>5][n][32], value W[k][n]) ----
  #pragma unroll 4
  for (int i = tid; i < 16384; i += 512){
    int k = i >> 7, n = i & 127;
    int a = ((k >> 5) * 128 + n) * 32 + (k & 31);
    wt1[a] = f2bf_rne(W1[i]);
    wt2[a] = f2bf_rne(W2[i]);
  }
  __syncthreads();   // weights visible

  // ---- layer 1: a1 = relu(h @ W1 + b1) ----
  {
    s16x8 bfr[4];
    #pragma unroll
    for (int ks = 0; ks < 4; ks++)
      bfr[ks] = *(const s16x8*)(wt1 + ((ks * 128 + (wv << 4) + l15) * 32 + (quad << 3)));
    float b1v = b1L[(wv << 4) + l15];
    int colhi = wv >> 1, collo = ((wv & 1) << 4) + l15;
    #pragma unroll
    for (int mt = 0; mt < 10; mt++){
      f32x4 acc = (f32x4){0.f, 0.f, 0.f, 0.f};
      #pragma unroll
      for (int ks = 0; ks < 4; ks++){
        s16x8 af = *(const s16x8*)(hB + ((ks * 160 + (mt << 4) + l15) * 32 + (quad << 3)));
        acc = __builtin_amdgcn_mfma_f32_16x16x32_bf16(af, bfr[ks], acc, 0, 0, 0);
      }
      #pragma unroll
      for (int r = 0; r < 4; r++){
        float v = fmaxf(acc[r] + b1v, 0.f);
        int row = (mt << 4) + (quad << 2) + r;
        a1B[(colhi * 160 + row) * 32 + collo] = f2bf_rne(v);
      }
    }
  }
  __syncthreads();   // a1 complete

  // ---- layer 2 + max over edges (registers only) ----
  {
    s16x8 bfr[4];
    #pragma unroll
    for (int ks = 0; ks < 4; ks++)
      bfr[ks] = *(const s16x8*)(wt2 + ((ks * 128 + (wv << 4) + l15) * 32 + (quad << 3)));
    float mxv[8];
    #pragma unroll
    for (int q = 0; q < 8; q++) mxv[q] = -3.0e38f;
    const int QA[10]  = {0,0,1,2,3,4,4,5,6,7};
    const int CUT[10] = {16,4,8,12,16,16,4,8,12,16};
    #pragma unroll
    for (int mt = 0; mt < 10; mt++){
      f32x4 acc = (f32x4){0.f, 0.f, 0.f, 0.f};
      #pragma unroll
      for (int ks = 0; ks < 4; ks++){
        s16x8 af = *(const s16x8*)(a1B + ((ks * 160 + (mt << 4) + l15) * 32 + (quad << 3)));
        acc = __builtin_amdgcn_mfma_f32_16x16x32_bf16(af, bfr[ks], acc, 0, 0, 0);
      }
      int qa = QA[mt], cut = CUT[mt];
      if (cut >= 16){
        #pragma unroll
        for (int r = 0; r < 4; r++) mxv[qa] = fmaxf(mxv[qa], acc[r]);
      } else {
        #pragma unroll
        for (int r = 0; r < 4; r++){
          int lr = (quad << 2) + r;
          bool toA = lr < cut;
          mxv[qa]     = fmaxf(mxv[qa],     toA ? acc[r] : -3.0e38f);
          mxv[qa + 1] = fmaxf(mxv[qa + 1], toA ? -3.0e38f : acc[r]);
        }
      }
    }
    // combine across quads (rows) -- all lanes end with full per-col max
    #pragma unroll
    for (int q = 0; q < 8; q++){
      float v = mxv[q];
      v = fmaxf(v, __shfl_xor(v, 16, 64));
      v = fmaxf(v, __shfl_xor(v, 32, 64));
      mxv[q] = v;
    }
    if (quad == 0){
      int col = (wv << 4) + l15;
      float b2v = b2L[col];
      #pragma unroll
      for (int q = 0; q < 8; q++)
        out[(size_t)(qid0 + q) * 128 + col] = mxv[q] + b2v;
    }
  }
}

// ---------------------------------------------------------------------------
// k_tail: pos[idx], batch[idx], lframes[idx] as fp32 at flat offsets.
// ---------------------------------------------------------------------------
__global__ __launch_bounds__(256) void k_tail(const float* __restrict__ pos,
    const float* __restrict__ lfr, float* __restrict__ out){
  int q = blockIdx.x * 256 + threadIdx.x;   // 0..16383
  int b = q >> 12;
  int node = (b << 14) + ((q & 4095) << 2);
  float* o_pos = out + 2097152;    // 16384*128
  float* o_bat = out + 2146304;    // + 16384*3
  float* o_lf  = out + 2162688;    // + 16384
  #pragma unroll
  for (int j = 0; j < 3; j++) o_pos[q * 3 + j] = pos[node * 3 + j];
  o_bat[q] = (float)b;
  #pragma unroll
  for (int j = 0; j < 9; j++) o_lf[q * 9 + j] = lfr[node * 9 + j];
}

extern "C" void kernel_launch(void* const* d_in, const int* in_sizes, int n_in,
                              void* d_out, int out_size, void* d_ws, size_t ws_size,
                              hipStream_t stream){
  const float* x   = (const float*)d_in[0];
  const float* pos = (const float*)d_in[1];
  const float* lfr = (const float*)d_in[2];
  // d_in[3] = batch (recomputed analytically)
  const float* W1  = (const float*)d_in[4];
  const float* b1  = (const float*)d_in[5];
  const float* W2  = (const float*)d_in[6];
  const float* b2  = (const float*)d_in[7];

  unsigned short* kfB = (unsigned short*)d_ws;
  float* normB = (float*)((char*)d_ws + WS_NORM);
  int*   nbr   = (int*)((char*)d_ws + WS_NBR);
  float* out = (float*)d_out;

  hipLaunchKernelGGL(k_prep, dim3(256),  dim3(256),  0, stream, x, pos, lfr, kfB, normB);
  hipLaunchKernelGGL(k_knn,  dim3(1024), dim3(512),  0, stream, kfB, normB, x, pos, lfr, nbr);
  hipLaunchKernelGGL(k_mlp,  dim3(2048), dim3(512),  0, stream, x, lfr, nbr, W1, b1, W2, b2, out);
  hipLaunchKernelGGL(k_tail, dim3(64),   dim3(256),  0, stream, pos, lfr, out);
}

// Round 10
// 673.541 us; speedup vs baseline: 1.4925x; 1.4754x over previous
//
#include <hip/hip_runtime.h>
#include <hip/hip_bf16.h>

// Problem constants
#define NTOT 65536      // B*N
#define KNN  20
#define KROW 104        // bf16 kf row stride (67 dims + pad) = 208 bytes

typedef __attribute__((ext_vector_type(4))) float f32x4;
typedef __attribute__((ext_vector_type(8))) short s16x8;

// ws layout (bytes): kfB bf16[65536][104] | normB f32[65536] | nbr i32
#define WS_NORM 13631488
#define WS_NBR  13893632

// ---- k_knn LDS map (bytes) ----
// buf: 144 rows x 257 dwords (256 columns + 1 pad for bank spread) = 148032
// col = qLocal*4 + kq   (qLocal 0..63 within block, kq = key quarter 0..3)
#define ROWS 144
#define CSTR 257
#define OFF_TAUG 149056     // unsigned tauG[64]
#define OFF_MG   149312     // unsigned mg[64*32] = 8192
#define KNN_SMEM 157504
#define THRESH 64           // compact when cntR > THRESH; checked every 4
                            // groups: 64 + 4*16 = 128 <= 144 rows (exact)

__device__ __forceinline__ unsigned short f2bf_rne(float v){
  unsigned u = __float_as_uint(v);
  return (unsigned short)((u + 0x7FFFu + ((u >> 16) & 1u)) >> 16);
}

// ---------------------------------------------------------------------------
// k_prep: kf = [s(16), R^T v(48), pos(3), -0.5|k|^2 as bf16 hi/lo] -> bf16
// rows (stride 104) + f32 norm. Dims 67/68 carry the norm so the d2 MFMA
// needs no separate ksq load (query side patches 1.0 into those dims).
// ---------------------------------------------------------------------------
__global__ __launch_bounds__(256) void k_prep(const float* __restrict__ x,
        const float* __restrict__ pos, const float* __restrict__ lfr,
        unsigned short* __restrict__ kfB, float* __restrict__ normB){
  int n = blockIdx.x * 256 + threadIdx.x;
  const float* xr = x + n * 64;
  float R[9];
  #pragma unroll
  for (int j = 0; j < 9; j++) R[j] = lfr[n * 9 + j];
  float c[67];
  #pragma unroll
  for (int i = 0; i < 16; i++) c[i] = xr[i];
  #pragma unroll
  for (int k = 0; k < 16; k++){
    float v0 = xr[16 + 3*k], v1 = xr[17 + 3*k], v2 = xr[18 + 3*k];
    #pragma unroll
    for (int a = 0; a < 3; a++)
      c[16 + 3*k + a] = R[a] * v0 + R[3 + a] * v1 + R[6 + a] * v2;  // R^T v
  }
  #pragma unroll
  for (int a = 0; a < 3; a++) c[64 + a] = pos[n * 3 + a];
  float sq = 0.f;
  #pragma unroll
  for (int d = 0; d < 67; d++) sq += c[d] * c[d];
  __attribute__((aligned(16))) unsigned short row[KROW];
  #pragma unroll
  for (int d = 0; d < 67; d++) row[d] = f2bf_rne(c[d]);
  #pragma unroll
  for (int d = 67; d < KROW; d++) row[d] = 0;
  // -0.5*|k|^2 split into bf16 hi/lo at dims 67,68
  {
    float h = -0.5f * sq;
    unsigned short hi = f2bf_rne(h);
    float hif = __uint_as_float(((unsigned)hi) << 16);
    row[67] = hi;
    row[68] = f2bf_rne(h - hif);
  }
  uint4* dst = (uint4*)(kfB + (size_t)n * KROW);
  const uint4* s4 = (const uint4*)row;
  #pragma unroll
  for (int i = 0; i < 13; i++) dst[i] = s4[i];
  normB[n] = sq;
}

// ---------------------------------------------------------------------------
// col_compact: exact top-32 (unique 32-bit packed values) of one column with
// cn (<=128) entries. 32-round ballot binary search for the 32nd smallest,
// then ballot-prefix rewrite. Wave-local, no barriers.
// ---------------------------------------------------------------------------
__device__ __forceinline__ unsigned col_compact(unsigned* buf,
    int col, int cn, int lane){
  unsigned e0 = (lane < cn) ? buf[lane * CSTR + col] : 0xFFFFFFFFu;
  unsigned e1 = (lane + 64 < cn) ? buf[(lane + 64) * CSTR + col] : 0xFFFFFFFFu;
  unsigned T = 0;
  #pragma unroll 1
  for (int b = 31; b >= 0; --b){
    unsigned cand = T | (1u << b);
    int c = __popcll(__ballot(e0 < cand)) + __popcll(__ballot(e1 < cand));
    if (c <= 31) T = cand;   // largest U with count(<U)<=31  ==> 32nd smallest
  }
  unsigned long long m0 = __ballot(e0 <= T);
  unsigned long long m1 = __ballot(e1 <= T);
  int b1 = __popcll(m0);
  unsigned long long ltm = (1ull << lane) - 1ull;
  if (e0 <= T) buf[__popcll(m0 & ltm) * CSTR + col] = e0;
  if (e1 <= T) buf[(b1 + __popcll(m1 & ltm)) * CSTR + col] = e1;
  return T;
}

// ---------------------------------------------------------------------------
// k_knn: the best-measured structure (421us): barrier-free wave-autonomous
// scan, 256 blocks x 1024 thr (16 waves). Wave (wq,kq): 16 queries x 4096
// keys. Keys direct from global (L2/L3-resident). Counts in quad-uniform
// registers; shared monotone tau via atomicMin, refreshed every 4 groups.
// Plus validated local wins: norm-folded keys (no nK load), tau-seed
// prologue, cheap-path guard in check_compact.
// ---------------------------------------------------------------------------
__global__ __launch_bounds__(1024, 4) void k_knn(
    const unsigned short* __restrict__ kfB, const float* __restrict__ normB,
    const float* __restrict__ x, const float* __restrict__ pos,
    const float* __restrict__ lfr, int* __restrict__ nbr){
  __shared__ __attribute__((aligned(16))) char smem[KNN_SMEM];
  unsigned* buf = (unsigned*)smem;
  unsigned* tauG = (unsigned*)(smem + OFF_TAUG);
  unsigned* mg = (unsigned*)(smem + OFF_MG);

  int tid = threadIdx.x;
  int blk = blockIdx.x;
  int b = blk & 3;                 // batch; XCD (blk%8) serves one batch slice
  int qloc0 = (blk >> 2) << 6;     // query block within batch: 0..4032
  int bbase = b << 14;

  if (tid < 64) tauG[tid] = 0x7F7FC000u;   // huge float (not NaN)

  int lane = tid & 63;
  int wv = tid >> 6;               // 0..15
  int wq = wv >> 2;                // query sub-group 0..3
  int kq = wv & 3;                 // key quarter 0..3
  int l15 = lane & 15, quad = lane >> 4;
  int colB = (wq << 6) + kq;       // col = colB + quad*16 + r*4

  // A fragments: wave's 16 queries; patch dims 67/68 -> 1.0 (norm-fold)
  int qloc = qloc0 + (wq << 4);
  s16x8 af[3];
  {
    int nodeA = bbase + ((qloc + l15) << 2);
    const unsigned short* ap = kfB + (size_t)nodeA * KROW + quad * 8;
    af[0] = *(const s16x8*)(ap);
    af[1] = *(const s16x8*)(ap + 32);
    af[2] = *(const s16x8*)(ap + 64);
  }
  if (quad == 0){ af[2][3] = (short)0x3F80; af[2][4] = (short)0x3F80; }
  float qsq[4];
  #pragma unroll
  for (int r = 0; r < 4; r++)
    qsq[r] = normB[bbase + ((qloc + (quad << 2) + r) << 2)];

  float tauR[4] = {3.0e38f, 3.0e38f, 3.0e38f, 3.0e38f};
  int cntR[4];                     // quad-uniform per-column counts (registers)

  // per-lane key stream base: key (kq*4096 + g*16 + l15), bytes quad*16..+48
  const unsigned short* kp = kfB
      + (size_t)(bbase + (kq << 12) + l15) * KROW + quad * 8;

  __syncthreads();   // tauG init visible

  s16x8 cK[4][3];
  #define LOADK(S) do { \
      cK[S][0] = *(const s16x8*)(kp); \
      cK[S][1] = *(const s16x8*)(kp + 32); \
      cK[S][2] = *(const s16x8*)(kp + 64); \
      kp += 16 * KROW; } while (0)

  auto comp = [&](const s16x8 bf[3], float d2v[4]){
    f32x4 acc = (f32x4){0.f, 0.f, 0.f, 0.f};
    acc = __builtin_amdgcn_mfma_f32_16x16x32_bf16(af[0], bf[0], acc, 0, 0, 0);
    acc = __builtin_amdgcn_mfma_f32_16x16x32_bf16(af[1], bf[1], acc, 0, 0, 0);
    acc = __builtin_amdgcn_mfma_f32_16x16x32_bf16(af[2], bf[2], acc, 0, 0, 0);
    #pragma unroll
    for (int r = 0; r < 4; r++)                      // d2 = |q|^2 - 2*acc
      d2v[r] = fmaxf(fmaf(-2.f, acc[r], qsq[r]), 0.f);
  };

  auto seed = [&](const float d2v[4], int g){
    int kidx = (kq << 12) + (g << 4) + l15;
    #pragma unroll
    for (int r = 0; r < 4; r++){
      unsigned pk = ((__float_as_uint(d2v[r]) + 0x2000u) & 0xFFFFC000u) | (unsigned)kidx;
      buf[((g << 4) + l15) * CSTR + colB + (quad << 4) + (r << 2)] = pk;
    }
  };

  auto process = [&](const float d2v[4], int g){
    bool p[4];
    #pragma unroll
    for (int r = 0; r < 4; r++) p[r] = d2v[r] < tauR[r];
    if (__any(p[0] | p[1] | p[2] | p[3])){
      int kidx = (kq << 12) + (g << 4) + l15;
      #pragma unroll
      for (int r = 0; r < 4; r++){
        unsigned long long m = __ballot(p[r]);
        if (m){
          int lo = (int)((m >> (quad << 4)) & 0xFFFFull);
          if (lo){
            int colr = colB + (quad << 4) + (r << 2);
            int pre = __popc(lo & ((1 << l15) - 1));
            if (p[r]){
              unsigned pk = ((__float_as_uint(d2v[r]) + 0x2000u) & 0xFFFFC000u) | (unsigned)kidx;
              buf[(cntR[r] + pre) * CSTR + colr] = pk;
            }
            cntR[r] += __popc(lo);      // quad-uniform update, no atomics
          }
        }
      }
    }
  };

  auto check_compact = [&](int limit){
    bool over = (cntR[0] > limit) | (cntR[1] > limit)
              | (cntR[2] > limit) | (cntR[3] > limit);
    if (!__any(over)) return;           // cheap common path: 1 ballot
    #pragma unroll
    for (int r = 0; r < 4; r++){
      unsigned long long mr = __ballot(cntR[r] > limit);
      while (mr){
        int ldr = __ffsll((unsigned long long)mr) - 1;
        int qd = ldr >> 4;
        mr &= ~(0xFFFFull << (qd << 4));
        int col = colB + (qd << 4) + (r << 2);
        int cn = __shfl(cntR[r], qd << 4, 64);
        unsigned T = col_compact(buf, col, cn, lane);
        if (quad == qd) cntR[r] = 32;
        if (lane == 0) atomicMin(&tauG[(wq << 4) + (qd << 2) + r], T);
      }
    }
  };

  auto tau_refresh = [&](){
    uint4 tg = *(const uint4*)&tauG[(wq << 4) + (quad << 2)];
    tauR[0] = __uint_as_float(tg.x & 0xFFFFC000u);
    tauR[1] = __uint_as_float(tg.y & 0xFFFFC000u);
    tauR[2] = __uint_as_float(tg.z & 0xFFFFC000u);
    tauR[3] = __uint_as_float(tg.w & 0xFFFFC000u);
  };

  // ---- prologue: fill 4 slots, seed groups 0..3; tau-seed compact ----
  float d2v[4];
  LOADK(0); LOADK(1); LOADK(2); LOADK(3);    // g0..g3
  #pragma unroll
  for (int j = 0; j < 4; j++){
    comp(cK[j], d2v);
    seed(d2v, j);
    LOADK(j);                                 // prefetch g4..g7
  }
  #pragma unroll
  for (int r = 0; r < 4; r++) cntR[r] = 64;
  check_compact(63);        // every column 64 -> 32; tauG seeded immediately
  tau_refresh();

  // ---- main scan: 4 groups/iter, 4-deep register prefetch ----
  #pragma unroll 1
  for (int g = 4; g < 256; g += 4){
    #pragma unroll
    for (int j = 0; j < 4; j++){
      comp(cK[j], d2v);
      LOADK(j);                               // prefetch g+4+j (tail overruns into valid ws)
      process(d2v, g + j);
    }
    check_compact(THRESH);
    tau_refresh();
  }

  // ---- final per-column exact top-32 (every column ends at exactly 32) ----
  check_compact(32);
  __syncthreads();

  // ---- per-query merge of 4 columns (4x32 = 128 fixed) -> top-32 into mg ----
  #pragma unroll 1
  for (int s = 0; s < 4; s++){
    int q = (wv << 2) + s;           // 0..63
    unsigned e0 = buf[(lane & 31) * CSTR + (q << 2) + (lane >> 5)];
    unsigned e1 = buf[(lane & 31) * CSTR + (q << 2) + 2 + (lane >> 5)];
    unsigned T = 0;
    #pragma unroll 1
    for (int bb = 31; bb >= 0; --bb){
      unsigned cand = T | (1u << bb);
      int c = __popcll(__ballot(e0 < cand)) + __popcll(__ballot(e1 < cand));
      if (c <= 31) T = cand;
    }
    unsigned long long m0 = __ballot(e0 <= T);
    unsigned long long m1 = __ballot(e1 <= T);
    int b1 = __popcll(m0);
    unsigned long long ltm = (1ull << lane) - 1ull;
    int p0 = __popcll(m0 & ltm);
    int p1 = b1 + __popcll(m1 & ltm);
    if ((e0 <= T) && (p0 < 32)) mg[(q << 5) + p0] = e0;
    if ((e1 <= T) && (p1 < 32)) mg[(q << 5) + p1] = e1;
  }
  __syncthreads();

  // ---- fp64 exact rerank of 32 candidates/query (overlays buf region) ----
  double* qkf = (double*)(smem);
  double* rrD = (double*)(smem + 34304);
  int*    rrI = (int*)(smem + 50688);

  {
    int t16 = tid & 15, q = tid >> 4;
    int node = bbase + ((qloc0 + q) << 2);
    const float* xr = x + node * 64;
    for (int dd = t16; dd < 67; dd += 16){
      double val;
      if (dd < 16) val = (double)xr[dd];
      else if (dd < 64){
        int r = dd - 16; int k = r / 3; int a = r - 3 * k;
        val = (double)lfr[node*9 + a]     * (double)xr[16 + 3*k]
            + (double)lfr[node*9 + 3 + a] * (double)xr[17 + 3*k]
            + (double)lfr[node*9 + 6 + a] * (double)xr[18 + 3*k];
      } else val = (double)pos[node*3 + (dd - 64)];
      qkf[q * 67 + dd] = val;
    }
  }
  __syncthreads();
  {
    int t16 = tid & 15, q = tid >> 4;
    for (int j = t16; j < 32; j += 16){
      int idx = (int)(mg[(q << 5) + j] & 0x3FFFu);
      int node = bbase + idx;
      const float* xr = x + node * 64;
      double R[9];
      #pragma unroll
      for (int t = 0; t < 9; t++) R[t] = (double)lfr[node * 9 + t];
      double d2 = 0.0;
      #pragma unroll
      for (int dd = 0; dd < 16; dd++){ double t = (double)xr[dd] - qkf[q*67 + dd]; d2 += t * t; }
      #pragma unroll
      for (int k = 0; k < 16; k++){
        double v0 = xr[16 + 3*k], v1 = xr[17 + 3*k], v2 = xr[18 + 3*k];
        #pragma unroll
        for (int a = 0; a < 3; a++){
          double val = R[a] * v0 + R[3 + a] * v1 + R[6 + a] * v2;
          double t = val - qkf[q*67 + 16 + 3*k + a]; d2 += t * t;
        }
      }
      #pragma unroll
      for (int a = 0; a < 3; a++){ double t = (double)pos[node*3 + a] - qkf[q*67 + 64 + a]; d2 += t * t; }
      rrD[q * 32 + j] = d2; rrI[q * 32 + j] = idx;
    }
  }
  __syncthreads();
  if (tid < 64){
    int qq = tid;
    int qid = (b << 12) + qloc0 + qq;
    #pragma unroll 1
    for (int s = 0; s < KNN; s++){
      double best = rrD[qq * 32 + s]; int bi = s;
      for (int t = s + 1; t < 32; t++){
        double v = rrD[qq * 32 + t]; if (v < best){ best = v; bi = t; }
      }
      double tv = rrD[qq * 32 + bi]; rrD[qq * 32 + bi] = rrD[qq * 32 + s]; rrD[qq * 32 + s] = tv;
      int ti = rrI[qq * 32 + bi]; rrI[qq * 32 + bi] = rrI[qq * 32 + s]; rrI[qq * 32 + s] = ti;
      nbr[qid * KNN + s] = bbase + rrI[qq * 32 + s];
    }
  }
}

// ---------------------------------------------------------------------------
// k_mlp (MFMA rewrite): 8 queries/block = 160 edge-rows (10 m-tiles), 512 thr
// (8 waves, wave wv owns 16 output cols). bf16 MFMA both layers, fp32 acc.
// LDS k-blocked layouts [k/32][row][32] (16B-aligned b128 frags, 2-way banks).
// Max-over-20-edges fully in registers via compile-time query-boundary masks.
// ---------------------------------------------------------------------------
#define M_X   0         // xs f32[160][68] = 43520 ; later Wt2 bf16[4][128][32]
#define M_H   43520     // hB bf16[4][160][32] = 40960
#define M_A1  84480     // a1B bf16[4][160][32] = 40960 (early: nbrL/xdL/lfL overlay)
#define M_W   125440    // Wt1 bf16[4][128][32] = 32768
#define M_B1  158208    // b1 f32[128]
#define M_B2  158720    // b2 f32[128]
#define M_SZ  159232

__global__ __launch_bounds__(512) void k_mlp(const float* __restrict__ x,
    const float* __restrict__ lfr, const int* __restrict__ nbr,
    const float* __restrict__ W1, const float* __restrict__ b1,
    const float* __restrict__ W2, const float* __restrict__ b2,
    float* __restrict__ out){
  __shared__ __attribute__((aligned(16))) char smem[M_SZ];
  float* xsF = (float*)(smem + M_X);
  unsigned short* hB = (unsigned short*)(smem + M_H);
  unsigned short* a1B = (unsigned short*)(smem + M_A1);
  unsigned short* wt1 = (unsigned short*)(smem + M_W);
  unsigned short* wt2 = (unsigned short*)(smem + M_X);
  float* b1L = (float*)(smem + M_B1);
  float* b2L = (float*)(smem + M_B2);
  int*   nbrL = (int*)(smem + M_A1);            // overlay (dead before a1 writes)
  float* xdL  = (float*)(smem + M_A1 + 640);    // 8x64 f32
  float* lfL  = (float*)(smem + M_A1 + 2688);   // 8x9 f32

  int tid = threadIdx.x;
  int qid0 = blockIdx.x * 8;
  int lane = tid & 63, wv = tid >> 6;
  int l15 = lane & 15, quad = lane >> 4;

  // ---- init loads ----
  if (tid < 160) nbrL[tid] = nbr[qid0 * 20 + tid];
  {
    int q = tid >> 6, d = tid & 63;
    int qid = qid0 + q;
    int node = ((qid >> 12) << 14) + ((qid & 4095) << 2);
    xdL[q * 64 + d] = x[node * 64 + d];
  }
  if (tid < 72){
    int q = tid / 9, j = tid - 9 * q;
    int qid = qid0 + q;
    int node = ((qid >> 12) << 14) + ((qid & 4095) << 2);
    lfL[q * 9 + j] = lfr[node * 9 + j];
  }
  if (tid < 128){ b1L[tid] = b1[tid]; b2L[tid] = b2[tid]; }
  __syncthreads();

  // ---- gather x_src into xs (160 rows x 64 f32, stride 68) ----
  {
    int f4 = tid & 15;
    #pragma unroll
    for (int p = 0; p < 5; p++){
      int e = (tid >> 4) + (p << 5);
      float4 v = *(const float4*)&x[(size_t)nbrL[e] * 64 + (f4 << 2)];
      *(float4*)&xsF[e * 68 + (f4 << 2)] = v;
    }
  }
  __syncthreads();

  // ---- build h bf16 into hB [d>>5][e][d&31] ----
  {
    int d = tid & 127, eo = tid >> 7;   // eo 0..3
    int cls, kk = 0, aa = 0;
    if (d < 64) cls = 0;
    else { int dd = d - 64;
      if (dd < 16) cls = 1;
      else { cls = 2; int r = dd - 16; kk = (r * 21846) >> 16; aa = r - 3 * kk; } }
    int hoff = ((d >> 5) * 160) * 32 + (d & 31);
    #pragma unroll 4
    for (int p = 0; p < 40; p++){
      int e = eo + (p << 2);
      int q = (e * 3277) >> 16;       // e/20 for e<160
      float v;
      if (cls == 0) v = xdL[q * 64 + d];
      else if (cls == 1) v = xsF[e * 68 + (d - 64)] - xdL[q * 64 + (d - 64)];
      else {
        int base = 16 + 3 * kk;
        float u0 = xsF[e * 68 + base]     - xdL[q * 64 + base];
        float u1 = xsF[e * 68 + base + 1] - xdL[q * 64 + base + 1];
        float u2 = xsF[e * 68 + base + 2] - xdL[q * 64 + base + 2];
        v = lfL[q * 9 + aa * 3] * u0 + lfL[q * 9 + aa * 3 + 1] * u1 + lfL[q * 9 + aa * 3 + 2] * u2;
      }
      hB[hoff + e * 32] = f2bf_rne(v);
    }
  }
  __syncthreads();   // hB done; xs/xdL/lfL/nbrL dead

  // ---- stage Wt1 -> M_W, Wt2 -> M_X  (layout [k>>5][n][32], value W[k][n]) ----
  #pragma unroll 4
  for (int i = tid; i < 16384; i += 512){
    int k = i >> 7, n = i & 127;
    int a = ((k >> 5) * 128 + n) * 32 + (k & 31);
    wt1[a] = f2bf_rne(W1[i]);
    wt2[a] = f2bf_rne(W2[i]);
  }
  __syncthreads();   // weights visible

  // ---- layer 1: a1 = relu(h @ W1 + b1) ----
  {
    s16x8 bfr[4];
    #pragma unroll
    for (int ks = 0; ks < 4; ks++)
      bfr[ks] = *(const s16x8*)(wt1 + ((ks * 128 + (wv << 4) + l15) * 32 + (quad << 3)));
    float b1v = b1L[(wv << 4) + l15];
    int colhi = wv >> 1, collo = ((wv & 1) << 4) + l15;
    #pragma unroll
    for (int mt = 0; mt < 10; mt++){
      f32x4 acc = (f32x4){0.f, 0.f, 0.f, 0.f};
      #pragma unroll
      for (int ks = 0; ks < 4; ks++){
        s16x8 af = *(const s16x8*)(hB + ((ks * 160 + (mt << 4) + l15) * 32 + (quad << 3)));
        acc = __builtin_amdgcn_mfma_f32_16x16x32_bf16(af, bfr[ks], acc, 0, 0, 0);
      }
      #pragma unroll
      for (int r = 0; r < 4; r++){
        float v = fmaxf(acc[r] + b1v, 0.f);
        int row = (mt << 4) + (quad << 2) + r;
        a1B[(colhi * 160 + row) * 32 + collo] = f2bf_rne(v);
      }
    }
  }
  __syncthreads();   // a1 complete

  // ---- layer 2 + max over edges (registers only) ----
  {
    s16x8 bfr[4];
    #pragma unroll
    for (int ks = 0; ks < 4; ks++)
      bfr[ks] = *(const s16x8*)(wt2 + ((ks * 128 + (wv << 4) + l15) * 32 + (quad << 3)));
    float mxv[8];
    #pragma unroll
    for (int q = 0; q < 8; q++) mxv[q] = -3.0e38f;
    const int QA[10]  = {0,0,1,2,3,4,4,5,6,7};
    const int CUT[10] = {16,4,8,12,16,16,4,8,12,16};
    #pragma unroll
    for (int mt = 0; mt < 10; mt++){
      f32x4 acc = (f32x4){0.f, 0.f, 0.f, 0.f};
      #pragma unroll
      for (int ks = 0; ks < 4; ks++){
        s16x8 af = *(const s16x8*)(a1B + ((ks * 160 + (mt << 4) + l15) * 32 + (quad << 3)));
        acc = __builtin_amdgcn_mfma_f32_16x16x32_bf16(af, bfr[ks], acc, 0, 0, 0);
      }
      int qa = QA[mt], cut = CUT[mt];
      if (cut >= 16){
        #pragma unroll
        for (int r = 0; r < 4; r++) mxv[qa] = fmaxf(mxv[qa], acc[r]);
      } else {
        #pragma unroll
        for (int r = 0; r < 4; r++){
          int lr = (quad << 2) + r;
          bool toA = lr < cut;
          mxv[qa]     = fmaxf(mxv[qa],     toA ? acc[r] : -3.0e38f);
          mxv[qa + 1] = fmaxf(mxv[qa + 1], toA ? -3.0e38f : acc[r]);
        }
      }
    }
    // combine across quads (rows) -- all lanes end with full per-col max
    #pragma unroll
    for (int q = 0; q < 8; q++){
      float v = mxv[q];
      v = fmaxf(v, __shfl_xor(v, 16, 64));
      v = fmaxf(v, __shfl_xor(v, 32, 64));
      mxv[q] = v;
    }
    if (quad == 0){
      int col = (wv << 4) + l15;
      float b2v = b2L[col];
      #pragma unroll
      for (int q = 0; q < 8; q++)
        out[(size_t)(qid0 + q) * 128 + col] = mxv[q] + b2v;
    }
  }
}

// ---------------------------------------------------------------------------
// k_tail: pos[idx], batch[idx], lframes[idx] as fp32 at flat offsets.
// ---------------------------------------------------------------------------
__global__ __launch_bounds__(256) void k_tail(const float* __restrict__ pos,
    const float* __restrict__ lfr, float* __restrict__ out){
  int q = blockIdx.x * 256 + threadIdx.x;   // 0..16383
  int b = q >> 12;
  int node = (b << 14) + ((q & 4095) << 2);
  float* o_pos = out + 2097152;    // 16384*128
  float* o_bat = out + 2146304;    // + 16384*3
  float* o_lf  = out + 2162688;    // + 16384
  #pragma unroll
  for (int j = 0; j < 3; j++) o_pos[q * 3 + j] = pos[node * 3 + j];
  o_bat[q] = (float)b;
  #pragma unroll
  for (int j = 0; j < 9; j++) o_lf[q * 9 + j] = lfr[node * 9 + j];
}

extern "C" void kernel_launch(void* const* d_in, const int* in_sizes, int n_in,
                              void* d_out, int out_size, void* d_ws, size_t ws_size,
                              hipStream_t stream){
  const float* x   = (const float*)d_in[0];
  const float* pos = (const float*)d_in[1];
  const float* lfr = (const float*)d_in[2];
  // d_in[3] = batch (recomputed analytically)
  const float* W1  = (const float*)d_in[4];
  const float* b1  = (const float*)d_in[5];
  const float* W2  = (const float*)d_in[6];
  const float* b2  = (const float*)d_in[7];

  unsigned short* kfB = (unsigned short*)d_ws;
  float* normB = (float*)((char*)d_ws + WS_NORM);
  int*   nbr   = (int*)((char*)d_ws + WS_NBR);
  float* out = (float*)d_out;

  hipLaunchKernelGGL(k_prep, dim3(256),  dim3(256),  0, stream, x, pos, lfr, kfB, normB);
  hipLaunchKernelGGL(k_knn,  dim3(256),  dim3(1024), 0, stream, kfB, normB, x, pos, lfr, nbr);
  hipLaunchKernelGGL(k_mlp,  dim3(2048), dim3(512),  0, stream, x, lfr, nbr, W1, b1, W2, b2, out);
  hipLaunchKernelGGL(k_tail, dim3(64),   dim3(256),  0, stream, pos, lfr, out);
}

// Round 11
// 604.105 us; speedup vs baseline: 1.6641x; 1.1149x over previous
//
#include <hip/hip_runtime.h>
#include <hip/hip_bf16.h>

// Problem constants
#define NTOT 65536      // B*N
#define KNN  20
#define KROW 104        // bf16 kf row stride (67 dims + pad)

typedef __attribute__((ext_vector_type(4))) float f32x4;
typedef __attribute__((ext_vector_type(8))) short s16x8;

// ws layout (bytes): kfB bf16[65536][104] | normB f32[65536] | nbr i32 |
//                    wb1 bf16[16384] | wb2 bf16[16384]
#define WS_NORM 13631488
#define WS_NBR  13893632
#define WS_WT1  15204352
#define WS_WT2  15237120

// ---- k_knn LDS map (bytes) ----
// buf: 144 rows x 257 dwords (256 columns + 1 pad for bank spread) = 148032
// col = qLocal*4 + kq   (qLocal 0..63 within block, kq = key quarter 0..3)
#define ROWS 144
#define CSTR 257
#define OFF_TAUG 149056     // unsigned tauG[64]
#define OFF_MG   149312     // unsigned mg[64*32]
#define KNN_SMEM 157504
#define THRESH 64           // compact a column when cnt > THRESH (max cn 96 <= 128)

__device__ __forceinline__ unsigned short f2bf_rne(float v){
  unsigned u = __float_as_uint(v);
  return (unsigned short)((u + 0x7FFFu + ((u >> 16) & 1u)) >> 16);
}

// ---------------------------------------------------------------------------
// k_prep: kf = [s(16), R^T v(48), pos(3)] -> bf16 rows (stride 104) + f32 norm
// (exact R3 version -- the 421us-measured configuration)
// ---------------------------------------------------------------------------
__global__ __launch_bounds__(256) void k_prep(const float* __restrict__ x,
        const float* __restrict__ pos, const float* __restrict__ lfr,
        unsigned short* __restrict__ kfB, float* __restrict__ normB){
  int n = blockIdx.x * 256 + threadIdx.x;
  const float* xr = x + n * 64;
  float R[9];
  #pragma unroll
  for (int j = 0; j < 9; j++) R[j] = lfr[n * 9 + j];
  float c[67];
  #pragma unroll
  for (int i = 0; i < 16; i++) c[i] = xr[i];
  #pragma unroll
  for (int k = 0; k < 16; k++){
    float v0 = xr[16 + 3*k], v1 = xr[17 + 3*k], v2 = xr[18 + 3*k];
    #pragma unroll
    for (int a = 0; a < 3; a++)
      c[16 + 3*k + a] = R[a] * v0 + R[3 + a] * v1 + R[6 + a] * v2;  // R^T v
  }
  #pragma unroll
  for (int a = 0; a < 3; a++) c[64 + a] = pos[n * 3 + a];
  float sq = 0.f;
  #pragma unroll
  for (int d = 0; d < 67; d++) sq += c[d] * c[d];
  __attribute__((aligned(16))) unsigned short row[KROW];
  #pragma unroll
  for (int d = 0; d < 67; d++) row[d] = f2bf_rne(c[d]);
  #pragma unroll
  for (int d = 67; d < KROW; d++) row[d] = 0;
  uint4* dst = (uint4*)(kfB + (size_t)n * KROW);
  const uint4* s4 = (const uint4*)row;
  #pragma unroll
  for (int i = 0; i < 13; i++) dst[i] = s4[i];
  normB[n] = sq;
}

// ---------------------------------------------------------------------------
// k_wprep: pre-convert W1/W2 (f32, row-major [128][128]) to bf16 in the
// k_mlp LDS layout a = ((k>>5)*128 + n)*32 + (k&31). Coalesced writes.
// ---------------------------------------------------------------------------
__global__ __launch_bounds__(256) void k_wprep(const float* __restrict__ W1,
        const float* __restrict__ W2, unsigned short* __restrict__ wb1,
        unsigned short* __restrict__ wb2){
  int a = blockIdx.x * 256 + threadIdx.x;      // 0..16383
  int kb = a >> 12, n = (a >> 5) & 127, kl = a & 31;
  int i = ((kb << 5) + kl) * 128 + n;
  wb1[a] = f2bf_rne(W1[i]);
  wb2[a] = f2bf_rne(W2[i]);
}

// ---------------------------------------------------------------------------
// col_compact: exact top-32 (by full 32-bit packed value) of one column with
// cn (<=128) entries. 32-round ballot binary search for the 32nd smallest,
// then ballot-prefix filter rewrite. Wave-local, no barriers.
// ---------------------------------------------------------------------------
__device__ __forceinline__ unsigned col_compact(unsigned* buf,
    int col, int cn, int lane){
  unsigned e0 = (lane < cn) ? buf[lane * CSTR + col] : 0xFFFFFFFFu;
  unsigned e1 = (lane + 64 < cn) ? buf[(lane + 64) * CSTR + col] : 0xFFFFFFFFu;
  unsigned T = 0;
  #pragma unroll 1
  for (int b = 31; b >= 0; --b){
    unsigned cand = T | (1u << b);
    int c = __popcll(__ballot(e0 < cand)) + __popcll(__ballot(e1 < cand));
    if (c <= 31) T = cand;   // largest U with count(<U)<=31  ==> 32nd smallest
  }
  unsigned long long m0 = __ballot(e0 <= T);
  unsigned long long m1 = __ballot(e1 <= T);
  int b1 = __popcll(m0);
  unsigned long long ltm = (1ull << lane) - 1ull;
  if (e0 <= T) buf[__popcll(m0 & ltm) * CSTR + col] = e0;
  if (e1 <= T) buf[(b1 + __popcll(m1 & ltm)) * CSTR + col] = e1;
  return T;
}

// ---------------------------------------------------------------------------
// k_knn: EXACT R3 (421us-measured) kernel. Barrier-free wave-autonomous scan,
// 256 blocks x 1024 thr (16 waves). Wave (wq,kq): 16 queries x 4096 keys.
// Keys direct from global (L2-resident). Counts in quad-uniform registers;
// shared monotone tau via atomicMin, refreshed every 4 groups.
// ---------------------------------------------------------------------------
__global__ __launch_bounds__(1024, 4) void k_knn(
    const unsigned short* __restrict__ kfB, const float* __restrict__ normB,
    const float* __restrict__ x, const float* __restrict__ pos,
    const float* __restrict__ lfr, int* __restrict__ nbr){
  __shared__ __attribute__((aligned(16))) char smem[KNN_SMEM];
  unsigned* buf = (unsigned*)smem;
  unsigned* tauG = (unsigned*)(smem + OFF_TAUG);
  unsigned* mg = (unsigned*)(smem + OFF_MG);

  int tid = threadIdx.x;
  int blk = blockIdx.x;
  int b = blk & 3;                 // batch; XCD (blk%8) serves one batch slice
  int qloc0 = (blk >> 2) << 6;     // query block within batch: 0..4032
  int bbase = b << 14;

  if (tid < 64) tauG[tid] = 0x7F7FC000u;   // huge float (not NaN)

  int lane = tid & 63;
  int wv = tid >> 6;               // 0..15
  int wq = wv >> 2;                // query sub-group 0..3
  int kq = wv & 3;                 // key quarter 0..3
  int l15 = lane & 15, quad = lane >> 4;
  int colB = (wq << 6) + kq;       // col = colB + quad*16 + r*4

  // A fragments: wave's 16 queries
  int qloc = qloc0 + (wq << 4);
  s16x8 af[3];
  {
    int nodeA = bbase + ((qloc + l15) << 2);
    const unsigned short* ap = kfB + (size_t)nodeA * KROW + quad * 8;
    af[0] = *(const s16x8*)(ap);
    af[1] = *(const s16x8*)(ap + 32);
    af[2] = *(const s16x8*)(ap + 64);
  }
  float qsq[4];
  #pragma unroll
  for (int r = 0; r < 4; r++)
    qsq[r] = normB[bbase + ((qloc + (quad << 2) + r) << 2)];

  float tauR[4] = {3.0e38f, 3.0e38f, 3.0e38f, 3.0e38f};
  int cntR[4];                     // quad-uniform per-column counts (registers)

  // key stream pointers (lane l15 -> key (kq*4096 + g*16 + l15))
  const unsigned short* kp = kfB + (size_t)(bbase + (kq << 12) + l15) * KROW + quad * 8;
  const float* np = normB + (bbase + (kq << 12) + l15);

  __syncthreads();   // tauG init visible

  s16x8 cK[4][3];
  float nK[4];
  #define LOADK(S) do { \
      cK[S][0] = *(const s16x8*)(kp); \
      cK[S][1] = *(const s16x8*)(kp + 32); \
      cK[S][2] = *(const s16x8*)(kp + 64); \
      nK[S] = *np; kp += 16 * KROW; np += 16; } while (0)

  auto comp = [&](const s16x8 bf[3], float ksqv, float d2v[4]){
    f32x4 acc = (f32x4){0.f, 0.f, 0.f, 0.f};
    acc = __builtin_amdgcn_mfma_f32_16x16x32_bf16(af[0], bf[0], acc, 0, 0, 0);
    acc = __builtin_amdgcn_mfma_f32_16x16x32_bf16(af[1], bf[1], acc, 0, 0, 0);
    acc = __builtin_amdgcn_mfma_f32_16x16x32_bf16(af[2], bf[2], acc, 0, 0, 0);
    #pragma unroll
    for (int r = 0; r < 4; r++)
      d2v[r] = fmaxf(qsq[r] + ksqv - 2.f * acc[r], 0.f);
  };

  auto seed = [&](const float d2v[4], int g){
    int kidx = (kq << 12) + (g << 4) + l15;
    #pragma unroll
    for (int r = 0; r < 4; r++){
      unsigned pk = ((__float_as_uint(d2v[r]) + 0x2000u) & 0xFFFFC000u) | (unsigned)kidx;
      buf[((g << 4) + l15) * CSTR + colB + (quad << 4) + (r << 2)] = pk;
    }
  };

  auto process = [&](const float d2v[4], int g){
    bool p[4];
    #pragma unroll
    for (int r = 0; r < 4; r++) p[r] = d2v[r] < tauR[r];
    if (__any(p[0] | p[1] | p[2] | p[3])){
      int kidx = (kq << 12) + (g << 4) + l15;
      #pragma unroll
      for (int r = 0; r < 4; r++){
        unsigned long long m = __ballot(p[r]);
        if (m){
          int lo = (int)((m >> (quad << 4)) & 0xFFFFull);
          if (lo){
            int colr = colB + (quad << 4) + (r << 2);
            int pre = __popc(lo & ((1 << l15) - 1));
            if (p[r]){
              unsigned pk = ((__float_as_uint(d2v[r]) + 0x2000u) & 0xFFFFC000u) | (unsigned)kidx;
              buf[(cntR[r] + pre) * CSTR + colr] = pk;
            }
            cntR[r] += __popc(lo);      // quad-uniform update, no atomics
          }
        }
      }
    }
  };

  // compact any over-limit column (wave-cooperative), update tauG
  auto check_compact = [&](int limit){
    #pragma unroll
    for (int r = 0; r < 4; r++){
      unsigned long long mr = __ballot(cntR[r] > limit);
      while (mr){
        int ldr = __ffsll((unsigned long long)mr) - 1;
        int qd = ldr >> 4;
        mr &= ~(0xFFFFull << (qd << 4));
        int col = colB + (qd << 4) + (r << 2);
        int cn = __shfl(cntR[r], qd << 4, 64);
        unsigned T = col_compact(buf, col, cn, lane);
        if (quad == qd) cntR[r] = 32;
        if (lane == 0) atomicMin(&tauG[(wq << 4) + (qd << 2) + r], T);
      }
    }
  };

  // ---- prologue: fill 4 slots, seed groups 0..3 unconditionally ----
  float d2v[4];
  LOADK(0); LOADK(1); LOADK(2); LOADK(3);    // g0..g3
  #pragma unroll
  for (int j = 0; j < 4; j++){
    comp(cK[j], nK[j], d2v);
    seed(d2v, j);
    LOADK(j);                                 // prefetch g4..g7
  }
  #pragma unroll
  for (int r = 0; r < 4; r++) cntR[r] = 64;

  // ---- main scan: 4 groups/iter, 4-deep register prefetch ----
  #pragma unroll 1
  for (int g = 4; g < 256; g += 4){
    #pragma unroll
    for (int j = 0; j < 4; j++){
      comp(cK[j], nK[j], d2v);
      LOADK(j);                               // prefetch g+4+j (tail overrun reads valid ws bytes)
      process(d2v, g + j);
    }
    check_compact(THRESH);
    uint4 tg = *(const uint4*)&tauG[(wq << 4) + (quad << 2)];
    tauR[0] = __uint_as_float(tg.x & 0xFFFFC000u);
    tauR[1] = __uint_as_float(tg.y & 0xFFFFC000u);
    tauR[2] = __uint_as_float(tg.z & 0xFFFFC000u);
    tauR[3] = __uint_as_float(tg.w & 0xFFFFC000u);
  }

  // ---- final per-column exact top-32 ----
  check_compact(32);
  __syncthreads();

  // ---- per-query merge of 4 columns (4x32 = 128 fixed) -> top-32 into mg ----
  #pragma unroll 1
  for (int s = 0; s < 4; s++){
    int q = (wv << 2) + s;           // 0..63
    unsigned e0 = buf[(lane & 31) * CSTR + (q << 2) + (lane >> 5)];
    unsigned e1 = buf[(lane & 31) * CSTR + (q << 2) + 2 + (lane >> 5)];
    unsigned T = 0;
    #pragma unroll 1
    for (int bb = 31; bb >= 0; --bb){
      unsigned cand = T | (1u << bb);
      int c = __popcll(__ballot(e0 < cand)) + __popcll(__ballot(e1 < cand));
      if (c <= 31) T = cand;
    }
    unsigned long long m0 = __ballot(e0 <= T);
    unsigned long long m1 = __ballot(e1 <= T);
    int b1 = __popcll(m0);
    unsigned long long ltm = (1ull << lane) - 1ull;
    int p0 = __popcll(m0 & ltm);
    int p1 = b1 + __popcll(m1 & ltm);
    if ((e0 <= T) && (p0 < 32)) mg[(q << 5) + p0] = e0;
    if ((e1 <= T) && (p1 < 32)) mg[(q << 5) + p1] = e1;
  }
  __syncthreads();

  // ---- fp64 exact rerank of 32 candidates/query (overlays buf region) ----
  double* qkf = (double*)(smem);
  double* rrD = (double*)(smem + 34304);
  int*    rrI = (int*)(smem + 50688);

  {
    int t16 = tid & 15, q = tid >> 4;
    int node = bbase + ((qloc0 + q) << 2);
    const float* xr = x + node * 64;
    for (int dd = t16; dd < 67; dd += 16){
      double val;
      if (dd < 16) val = (double)xr[dd];
      else if (dd < 64){
        int r = dd - 16; int k = r / 3; int a = r - 3 * k;
        val = (double)lfr[node*9 + a]     * (double)xr[16 + 3*k]
            + (double)lfr[node*9 + 3 + a] * (double)xr[17 + 3*k]
            + (double)lfr[node*9 + 6 + a] * (double)xr[18 + 3*k];
      } else val = (double)pos[node*3 + (dd - 64)];
      qkf[q * 67 + dd] = val;
    }
  }
  __syncthreads();
  {
    int t16 = tid & 15, q = tid >> 4;
    for (int j = t16; j < 32; j += 16){
      int idx = (int)(mg[(q << 5) + j] & 0x3FFFu);
      int node = bbase + idx;
      const float* xr = x + node * 64;
      double R[9];
      #pragma unroll
      for (int t = 0; t < 9; t++) R[t] = (double)lfr[node * 9 + t];
      double d2 = 0.0;
      #pragma unroll
      for (int dd = 0; dd < 16; dd++){ double t = (double)xr[dd] - qkf[q*67 + dd]; d2 += t * t; }
      #pragma unroll
      for (int k = 0; k < 16; k++){
        double v0 = xr[16 + 3*k], v1 = xr[17 + 3*k], v2 = xr[18 + 3*k];
        #pragma unroll
        for (int a = 0; a < 3; a++){
          double val = R[a] * v0 + R[3 + a] * v1 + R[6 + a] * v2;
          double t = val - qkf[q*67 + 16 + 3*k + a]; d2 += t * t;
        }
      }
      #pragma unroll
      for (int a = 0; a < 3; a++){ double t = (double)pos[node*3 + a] - qkf[q*67 + 64 + a]; d2 += t * t; }
      rrD[q * 32 + j] = d2; rrI[q * 32 + j] = idx;
    }
  }
  __syncthreads();
  if (tid < 64){
    int qq = tid;
    int qid = (b << 12) + qloc0 + qq;
    #pragma unroll 1
    for (int s = 0; s < KNN; s++){
      double best = rrD[qq * 32 + s]; int bi = s;
      for (int t = s + 1; t < 32; t++){
        double v = rrD[qq * 32 + t]; if (v < best){ best = v; bi = t; }
      }
      double tv = rrD[qq * 32 + bi]; rrD[qq * 32 + bi] = rrD[qq * 32 + s]; rrD[qq * 32 + s] = tv;
      int ti = rrI[qq * 32 + bi]; rrI[qq * 32 + bi] = rrI[qq * 32 + s]; rrI[qq * 32 + s] = ti;
      nbr[qid * KNN + s] = bbase + rrI[qq * 32 + s];
    }
  }
}

// ---------------------------------------------------------------------------
// k_mlp: 8 queries/block = 160 edge-rows (10 m-tiles), 512 thr. bf16 MFMA
// both layers, fp32 acc. NEW: weights pre-converted by k_wprep; staged as
// 8 uint4 copies/thread at kernel start (overlapped with init loads, one
// fewer barrier, no per-block f32->bf16 conversion). a1B overlays dead xs;
// nbrL/xdL/lfL in dedicated tail region (no overlay hazards).
// ---------------------------------------------------------------------------
#define M_X   0         // xs f32[160][68] = 43520 ; later a1B bf16[4][160][32] = 40960
#define M_H   43520     // hB bf16[4][160][32] = 40960
#define M_W1  84480     // wt1 bf16[4][128][32] = 32768
#define M_W2  117248    // wt2 bf16[4][128][32] = 32768
#define M_B1  150016    // b1 f32[128]
#define M_B2  150528    // b2 f32[128]
#define M_NBR 151040    // nbrL i32[160] = 640
#define M_XD  151680    // xdL f32[8][64] = 2048
#define M_LF  153728    // lfL f32[8][9] = 288
#define M_SZ  154048

__global__ __launch_bounds__(512) void k_mlp(const float* __restrict__ x,
    const float* __restrict__ lfr, const int* __restrict__ nbr,
    const unsigned short* __restrict__ wb1, const unsigned short* __restrict__ wb2,
    const float* __restrict__ b1, const float* __restrict__ b2,
    float* __restrict__ out){
  __shared__ __attribute__((aligned(16))) char smem[M_SZ];
  float* xsF = (float*)(smem + M_X);
  unsigned short* a1B = (unsigned short*)(smem + M_X);   // overlays xs (dead)
  unsigned short* hB = (unsigned short*)(smem + M_H);
  unsigned short* wt1 = (unsigned short*)(smem + M_W1);
  unsigned short* wt2 = (unsigned short*)(smem + M_W2);
  float* b1L = (float*)(smem + M_B1);
  float* b2L = (float*)(smem + M_B2);
  int*   nbrL = (int*)(smem + M_NBR);
  float* xdL  = (float*)(smem + M_XD);
  float* lfL  = (float*)(smem + M_LF);

  int tid = threadIdx.x;
  int qid0 = blockIdx.x * 8;
  int lane = tid & 63, wv = tid >> 6;
  int l15 = lane & 15, quad = lane >> 4;

  // ---- init loads: weights (uint4 copies) + nbr/xd/lf/biases, one barrier ----
  {
    const uint4* g1 = (const uint4*)wb1;
    const uint4* g2 = (const uint4*)wb2;
    uint4* l1 = (uint4*)wt1;
    uint4* l2 = (uint4*)wt2;
    #pragma unroll
    for (int p = 0; p < 4; p++){
      l1[tid + (p << 9)] = g1[tid + (p << 9)];
      l2[tid + (p << 9)] = g2[tid + (p << 9)];
    }
  }
  if (tid < 160) nbrL[tid] = nbr[qid0 * 20 + tid];
  {
    int q = tid >> 6, d = tid & 63;
    int qid = qid0 + q;
    int node = ((qid >> 12) << 14) + ((qid & 4095) << 2);
    xdL[q * 64 + d] = x[node * 64 + d];
  }
  if (tid < 72){
    int q = tid / 9, j = tid - 9 * q;
    int qid = qid0 + q;
    int node = ((qid >> 12) << 14) + ((qid & 4095) << 2);
    lfL[q * 9 + j] = lfr[node * 9 + j];
  }
  if (tid < 128){ b1L[tid] = b1[tid]; b2L[tid] = b2[tid]; }
  __syncthreads();

  // ---- gather x_src into xs (160 rows x 64 f32, stride 68) ----
  {
    int f4 = tid & 15;
    #pragma unroll
    for (int p = 0; p < 5; p++){
      int e = (tid >> 4) + (p << 5);
      float4 v = *(const float4*)&x[(size_t)nbrL[e] * 64 + (f4 << 2)];
      *(float4*)&xsF[e * 68 + (f4 << 2)] = v;
    }
  }
  __syncthreads();

  // ---- build h bf16 into hB [d>>5][e][d&31] ----
  {
    int d = tid & 127, eo = tid >> 7;   // eo 0..3
    int cls, kk = 0, aa = 0;
    if (d < 64) cls = 0;
    else { int dd = d - 64;
      if (dd < 16) cls = 1;
      else { cls = 2; int r = dd - 16; kk = (r * 21846) >> 16; aa = r - 3 * kk; } }
    int hoff = ((d >> 5) * 160) * 32 + (d & 31);
    #pragma unroll 4
    for (int p = 0; p < 40; p++){
      int e = eo + (p << 2);
      int q = (e * 3277) >> 16;       // e/20 for e<160
      float v;
      if (cls == 0) v = xdL[q * 64 + d];
      else if (cls == 1) v = xsF[e * 68 + (d - 64)] - xdL[q * 64 + (d - 64)];
      else {
        int base = 16 + 3 * kk;
        float u0 = xsF[e * 68 + base]     - xdL[q * 64 + base];
        float u1 = xsF[e * 68 + base + 1] - xdL[q * 64 + base + 1];
        float u2 = xsF[e * 68 + base + 2] - xdL[q * 64 + base + 2];
        v = lfL[q * 9 + aa * 3] * u0 + lfL[q * 9 + aa * 3 + 1] * u1 + lfL[q * 9 + aa * 3 + 2] * u2;
      }
      hB[hoff + e * 32] = f2bf_rne(v);
    }
  }
  __syncthreads();   // hB done; xs dead (a1B may now be written)

  // ---- layer 1: a1 = relu(h @ W1 + b1) ----
  {
    s16x8 bfr[4];
    #pragma unroll
    for (int ks = 0; ks < 4; ks++)
      bfr[ks] = *(const s16x8*)(wt1 + ((ks * 128 + (wv << 4) + l15) * 32 + (quad << 3)));
    float b1v = b1L[(wv << 4) + l15];
    int colhi = wv >> 1, collo = ((wv & 1) << 4) + l15;
    #pragma unroll
    for (int mt = 0; mt < 10; mt++){
      f32x4 acc = (f32x4){0.f, 0.f, 0.f, 0.f};
      #pragma unroll
      for (int ks = 0; ks < 4; ks++){
        s16x8 af = *(const s16x8*)(hB + ((ks * 160 + (mt << 4) + l15) * 32 + (quad << 3)));
        acc = __builtin_amdgcn_mfma_f32_16x16x32_bf16(af, bfr[ks], acc, 0, 0, 0);
      }
      #pragma unroll
      for (int r = 0; r < 4; r++){
        float v = fmaxf(acc[r] + b1v, 0.f);
        int row = (mt << 4) + (quad << 2) + r;
        a1B[(colhi * 160 + row) * 32 + collo] = f2bf_rne(v);
      }
    }
  }
  __syncthreads();   // a1 complete

  // ---- layer 2 + max over edges (registers only) ----
  {
    s16x8 bfr[4];
    #pragma unroll
    for (int ks = 0; ks < 4; ks++)
      bfr[ks] = *(const s16x8*)(wt2 + ((ks * 128 + (wv << 4) + l15) * 32 + (quad << 3)));
    float mxv[8];
    #pragma unroll
    for (int q = 0; q < 8; q++) mxv[q] = -3.0e38f;
    const int QA[10]  = {0,0,1,2,3,4,4,5,6,7};
    const int CUT[10] = {16,4,8,12,16,16,4,8,12,16};
    #pragma unroll
    for (int mt = 0; mt < 10; mt++){
      f32x4 acc = (f32x4){0.f, 0.f, 0.f, 0.f};
      #pragma unroll
      for (int ks = 0; ks < 4; ks++){
        s16x8 af = *(const s16x8*)(a1B + ((ks * 160 + (mt << 4) + l15) * 32 + (quad << 3)));
        acc = __builtin_amdgcn_mfma_f32_16x16x32_bf16(af, bfr[ks], acc, 0, 0, 0);
      }
      int qa = QA[mt], cut = CUT[mt];
      if (cut >= 16){
        #pragma unroll
        for (int r = 0; r < 4; r++) mxv[qa] = fmaxf(mxv[qa], acc[r]);
      } else {
        #pragma unroll
        for (int r = 0; r < 4; r++){
          int lr = (quad << 2) + r;
          bool toA = lr < cut;
          mxv[qa]     = fmaxf(mxv[qa],     toA ? acc[r] : -3.0e38f);
          mxv[qa + 1] = fmaxf(mxv[qa + 1], toA ? -3.0e38f : acc[r]);
        }
      }
    }
    // combine across quads (rows) -- all lanes end with full per-col max
    #pragma unroll
    for (int q = 0; q < 8; q++){
      float v = mxv[q];
      v = fmaxf(v, __shfl_xor(v, 16, 64));
      v = fmaxf(v, __shfl_xor(v, 32, 64));
      mxv[q] = v;
    }
    if (quad == 0){
      int col = (wv << 4) + l15;
      float b2v = b2L[col];
      #pragma unroll
      for (int q = 0; q < 8; q++)
        out[(size_t)(qid0 + q) * 128 + col] = mxv[q] + b2v;
    }
  }
}

// ---------------------------------------------------------------------------
// k_tail: pos[idx], batch[idx], lframes[idx] as fp32 at flat offsets.
// ---------------------------------------------------------------------------
__global__ __launch_bounds__(256) void k_tail(const float* __restrict__ pos,
    const float* __restrict__ lfr, float* __restrict__ out){
  int q = blockIdx.x * 256 + threadIdx.x;   // 0..16383
  int b = q >> 12;
  int node = (b << 14) + ((q & 4095) << 2);
  float* o_pos = out + 2097152;    // 16384*128
  float* o_bat = out + 2146304;    // + 16384*3
  float* o_lf  = out + 2162688;    // + 16384
  #pragma unroll
  for (int j = 0; j < 3; j++) o_pos[q * 3 + j] = pos[node * 3 + j];
  o_bat[q] = (float)b;
  #pragma unroll
  for (int j = 0; j < 9; j++) o_lf[q * 9 + j] = lfr[node * 9 + j];
}

extern "C" void kernel_launch(void* const* d_in, const int* in_sizes, int n_in,
                              void* d_out, int out_size, void* d_ws, size_t ws_size,
                              hipStream_t stream){
  const float* x   = (const float*)d_in[0];
  const float* pos = (const float*)d_in[1];
  const float* lfr = (const float*)d_in[2];
  // d_in[3] = batch (recomputed analytically)
  const float* W1  = (const float*)d_in[4];
  const float* b1  = (const float*)d_in[5];
  const float* W2  = (const float*)d_in[6];
  const float* b2  = (const float*)d_in[7];

  unsigned short* kfB = (unsigned short*)d_ws;
  float* normB = (float*)((char*)d_ws + WS_NORM);
  int*   nbr   = (int*)((char*)d_ws + WS_NBR);
  unsigned short* wb1 = (unsigned short*)((char*)d_ws + WS_WT1);
  unsigned short* wb2 = (unsigned short*)((char*)d_ws + WS_WT2);
  float* out = (float*)d_out;

  hipLaunchKernelGGL(k_prep,  dim3(256),  dim3(256), 0, stream, x, pos, lfr, kfB, normB);
  hipLaunchKernelGGL(k_wprep, dim3(64),   dim3(256), 0, stream, W1, W2, wb1, wb2);
  hipLaunchKernelGGL(k_knn,   dim3(256),  dim3(1024), 0, stream, kfB, normB, x, pos, lfr, nbr);
  hipLaunchKernelGGL(k_mlp,   dim3(2048), dim3(512), 0, stream, x, lfr, nbr, wb1, wb2, b1, b2, out);
  hipLaunchKernelGGL(k_tail,  dim3(64),   dim3(256), 0, stream, pos, lfr, out);
}

// Round 12
// 597.352 us; speedup vs baseline: 1.6829x; 1.0113x over previous
//
#include <hip/hip_runtime.h>
#include <hip/hip_bf16.h>

// Problem constants
#define NTOT 65536      // B*N
#define KNN  20
#define KROW 104        // bf16 kf row stride (67 dims + pad)

typedef __attribute__((ext_vector_type(4))) float f32x4;
typedef __attribute__((ext_vector_type(8))) short s16x8;

// ws layout (bytes): kfB bf16[65536][104] | normB f32[65536] | nbr i32[16384*20]
//                  | wb1 bf16[16384] | wb2 bf16[16384] | mg u16[16384*32]
#define WS_NORM 13631488
#define WS_NBR  13893632
#define WS_WT1  15204352
#define WS_WT2  15237120
#define WS_MG   15269888    // 1 MB; ws end = 16318464 < 16 MiB

// ---- k_knn LDS map (bytes) ----
// buf: 144 rows x 257 dwords (256 columns + 1 pad for bank spread) = 148032
// col = qLocal*4 + kq   (qLocal 0..63 within block, kq = key quarter 0..3)
#define ROWS 144
#define CSTR 257
#define OFF_TAUG 149056     // unsigned tauG[64]
#define KNN_SMEM 149312
#define THRESH 64           // compact a column when cnt > THRESH (max cn 96 <= 128)

__device__ __forceinline__ unsigned short f2bf_rne(float v){
  unsigned u = __float_as_uint(v);
  return (unsigned short)((u + 0x7FFFu + ((u >> 16) & 1u)) >> 16);
}

// ---------------------------------------------------------------------------
// k_prep: kf = [s(16), R^T v(48), pos(3)] -> bf16 rows (stride 104) + f32 norm
// ---------------------------------------------------------------------------
__global__ __launch_bounds__(256) void k_prep(const float* __restrict__ x,
        const float* __restrict__ pos, const float* __restrict__ lfr,
        unsigned short* __restrict__ kfB, float* __restrict__ normB){
  int n = blockIdx.x * 256 + threadIdx.x;
  const float* xr = x + n * 64;
  float R[9];
  #pragma unroll
  for (int j = 0; j < 9; j++) R[j] = lfr[n * 9 + j];
  float c[67];
  #pragma unroll
  for (int i = 0; i < 16; i++) c[i] = xr[i];
  #pragma unroll
  for (int k = 0; k < 16; k++){
    float v0 = xr[16 + 3*k], v1 = xr[17 + 3*k], v2 = xr[18 + 3*k];
    #pragma unroll
    for (int a = 0; a < 3; a++)
      c[16 + 3*k + a] = R[a] * v0 + R[3 + a] * v1 + R[6 + a] * v2;  // R^T v
  }
  #pragma unroll
  for (int a = 0; a < 3; a++) c[64 + a] = pos[n * 3 + a];
  float sq = 0.f;
  #pragma unroll
  for (int d = 0; d < 67; d++) sq += c[d] * c[d];
  __attribute__((aligned(16))) unsigned short row[KROW];
  #pragma unroll
  for (int d = 0; d < 67; d++) row[d] = f2bf_rne(c[d]);
  #pragma unroll
  for (int d = 67; d < KROW; d++) row[d] = 0;
  uint4* dst = (uint4*)(kfB + (size_t)n * KROW);
  const uint4* s4 = (const uint4*)row;
  #pragma unroll
  for (int i = 0; i < 13; i++) dst[i] = s4[i];
  normB[n] = sq;
}

// ---------------------------------------------------------------------------
// k_wprep: pre-convert W1/W2 (f32, row-major [128][128]) to bf16 in the
// k_mlp LDS layout a = ((k>>5)*128 + n)*32 + (k&31). Coalesced writes.
// ---------------------------------------------------------------------------
__global__ __launch_bounds__(256) void k_wprep(const float* __restrict__ W1,
        const float* __restrict__ W2, unsigned short* __restrict__ wb1,
        unsigned short* __restrict__ wb2){
  int a = blockIdx.x * 256 + threadIdx.x;      // 0..16383
  int kb = a >> 12, n = (a >> 5) & 127, kl = a & 31;
  int i = ((kb << 5) + kl) * 128 + n;
  wb1[a] = f2bf_rne(W1[i]);
  wb2[a] = f2bf_rne(W2[i]);
}

// ---------------------------------------------------------------------------
// col_compact: exact top-32 (by full 32-bit packed value) of one column with
// cn (<=128) entries. 32-round ballot binary search for the 32nd smallest,
// then ballot-prefix filter rewrite. Wave-local, no barriers.
// ---------------------------------------------------------------------------
__device__ __forceinline__ unsigned col_compact(unsigned* buf,
    int col, int cn, int lane){
  unsigned e0 = (lane < cn) ? buf[lane * CSTR + col] : 0xFFFFFFFFu;
  unsigned e1 = (lane + 64 < cn) ? buf[(lane + 64) * CSTR + col] : 0xFFFFFFFFu;
  unsigned T = 0;
  #pragma unroll 1
  for (int b = 31; b >= 0; --b){
    unsigned cand = T | (1u << b);
    int c = __popcll(__ballot(e0 < cand)) + __popcll(__ballot(e1 < cand));
    if (c <= 31) T = cand;   // largest U with count(<U)<=31  ==> 32nd smallest
  }
  unsigned long long m0 = __ballot(e0 <= T);
  unsigned long long m1 = __ballot(e1 <= T);
  int b1 = __popcll(m0);
  unsigned long long ltm = (1ull << lane) - 1ull;
  if (e0 <= T) buf[__popcll(m0 & ltm) * CSTR + col] = e0;
  if (e1 <= T) buf[(b1 + __popcll(m1 & ltm)) * CSTR + col] = e1;
  return T;
}

// ---------------------------------------------------------------------------
// k_knn: R3 scan structure (421us-proven), epilogue SPLIT OUT. Barrier-free
// wave-autonomous scan, 256 blocks x 1024 thr (16 waves). Wave (wq,kq): 16
// queries x 4096 keys. Keys direct from global (L2-resident). Counts in
// quad-uniform registers; shared monotone tau via atomicMin, refreshed every
// 4 groups. Ends after the per-query merge, writing 32 candidate INDICES
// per query (u16) to ws; fp64 rerank moved to k_rerank (high-occupancy).
// ---------------------------------------------------------------------------
__global__ __launch_bounds__(1024, 4) void k_knn(
    const unsigned short* __restrict__ kfB, const float* __restrict__ normB,
    unsigned short* __restrict__ mgG){
  __shared__ __attribute__((aligned(16))) char smem[KNN_SMEM];
  unsigned* buf = (unsigned*)smem;
  unsigned* tauG = (unsigned*)(smem + OFF_TAUG);

  int tid = threadIdx.x;
  int blk = blockIdx.x;
  int b = blk & 3;                 // batch; XCD (blk%8) serves one batch slice
  int qloc0 = (blk >> 2) << 6;     // query block within batch: 0..4032
  int bbase = b << 14;

  if (tid < 64) tauG[tid] = 0x7F7FC000u;   // huge float (not NaN)

  int lane = tid & 63;
  int wv = tid >> 6;               // 0..15
  int wq = wv >> 2;                // query sub-group 0..3
  int kq = wv & 3;                 // key quarter 0..3
  int l15 = lane & 15, quad = lane >> 4;
  int colB = (wq << 6) + kq;       // col = colB + quad*16 + r*4

  // A fragments: wave's 16 queries
  int qloc = qloc0 + (wq << 4);
  s16x8 af[3];
  {
    int nodeA = bbase + ((qloc + l15) << 2);
    const unsigned short* ap = kfB + (size_t)nodeA * KROW + quad * 8;
    af[0] = *(const s16x8*)(ap);
    af[1] = *(const s16x8*)(ap + 32);
    af[2] = *(const s16x8*)(ap + 64);
  }
  float qsq[4];
  #pragma unroll
  for (int r = 0; r < 4; r++)
    qsq[r] = normB[bbase + ((qloc + (quad << 2) + r) << 2)];

  float tauR[4] = {3.0e38f, 3.0e38f, 3.0e38f, 3.0e38f};
  int cntR[4];                     // quad-uniform per-column counts (registers)

  // key stream pointers (lane l15 -> key (kq*4096 + g*16 + l15))
  const unsigned short* kp = kfB + (size_t)(bbase + (kq << 12) + l15) * KROW + quad * 8;
  const float* np = normB + (bbase + (kq << 12) + l15);

  __syncthreads();   // tauG init visible

  s16x8 cK[4][3];
  float nK[4];
  #define LOADK(S) do { \
      cK[S][0] = *(const s16x8*)(kp); \
      cK[S][1] = *(const s16x8*)(kp + 32); \
      cK[S][2] = *(const s16x8*)(kp + 64); \
      nK[S] = *np; kp += 16 * KROW; np += 16; } while (0)

  auto comp = [&](const s16x8 bf[3], float ksqv, float d2v[4]){
    f32x4 acc = (f32x4){0.f, 0.f, 0.f, 0.f};
    acc = __builtin_amdgcn_mfma_f32_16x16x32_bf16(af[0], bf[0], acc, 0, 0, 0);
    acc = __builtin_amdgcn_mfma_f32_16x16x32_bf16(af[1], bf[1], acc, 0, 0, 0);
    acc = __builtin_amdgcn_mfma_f32_16x16x32_bf16(af[2], bf[2], acc, 0, 0, 0);
    #pragma unroll
    for (int r = 0; r < 4; r++)
      d2v[r] = fmaxf(qsq[r] + ksqv - 2.f * acc[r], 0.f);
  };

  auto seed = [&](const float d2v[4], int g){
    int kidx = (kq << 12) + (g << 4) + l15;
    #pragma unroll
    for (int r = 0; r < 4; r++){
      unsigned pk = ((__float_as_uint(d2v[r]) + 0x2000u) & 0xFFFFC000u) | (unsigned)kidx;
      buf[((g << 4) + l15) * CSTR + colB + (quad << 4) + (r << 2)] = pk;
    }
  };

  auto process = [&](const float d2v[4], int g){
    bool p[4];
    #pragma unroll
    for (int r = 0; r < 4; r++) p[r] = d2v[r] < tauR[r];
    if (__any(p[0] | p[1] | p[2] | p[3])){
      int kidx = (kq << 12) + (g << 4) + l15;
      #pragma unroll
      for (int r = 0; r < 4; r++){
        unsigned long long m = __ballot(p[r]);
        if (m){
          int lo = (int)((m >> (quad << 4)) & 0xFFFFull);
          if (lo){
            int colr = colB + (quad << 4) + (r << 2);
            int pre = __popc(lo & ((1 << l15) - 1));
            if (p[r]){
              unsigned pk = ((__float_as_uint(d2v[r]) + 0x2000u) & 0xFFFFC000u) | (unsigned)kidx;
              buf[(cntR[r] + pre) * CSTR + colr] = pk;
            }
            cntR[r] += __popc(lo);      // quad-uniform update, no atomics
          }
        }
      }
    }
  };

  // compact any over-limit column (wave-cooperative), update tauG
  auto check_compact = [&](int limit){
    #pragma unroll
    for (int r = 0; r < 4; r++){
      unsigned long long mr = __ballot(cntR[r] > limit);
      while (mr){
        int ldr = __ffsll((unsigned long long)mr) - 1;
        int qd = ldr >> 4;
        mr &= ~(0xFFFFull << (qd << 4));
        int col = colB + (qd << 4) + (r << 2);
        int cn = __shfl(cntR[r], qd << 4, 64);
        unsigned T = col_compact(buf, col, cn, lane);
        if (quad == qd) cntR[r] = 32;
        if (lane == 0) atomicMin(&tauG[(wq << 4) + (qd << 2) + r], T);
      }
    }
  };

  // ---- prologue: fill 4 slots, seed groups 0..3 unconditionally ----
  float d2v[4];
  LOADK(0); LOADK(1); LOADK(2); LOADK(3);    // g0..g3
  #pragma unroll
  for (int j = 0; j < 4; j++){
    comp(cK[j], nK[j], d2v);
    seed(d2v, j);
    LOADK(j);                                 // prefetch g4..g7
  }
  #pragma unroll
  for (int r = 0; r < 4; r++) cntR[r] = 64;

  // ---- main scan: 4 groups/iter, 4-deep register prefetch ----
  #pragma unroll 1
  for (int g = 4; g < 256; g += 4){
    #pragma unroll
    for (int j = 0; j < 4; j++){
      comp(cK[j], nK[j], d2v);
      LOADK(j);                               // prefetch g+4+j (tail overrun reads valid ws bytes)
      process(d2v, g + j);
    }
    check_compact(THRESH);
    uint4 tg = *(const uint4*)&tauG[(wq << 4) + (quad << 2)];
    tauR[0] = __uint_as_float(tg.x & 0xFFFFC000u);
    tauR[1] = __uint_as_float(tg.y & 0xFFFFC000u);
    tauR[2] = __uint_as_float(tg.z & 0xFFFFC000u);
    tauR[3] = __uint_as_float(tg.w & 0xFFFFC000u);
  }

  // ---- final per-column exact top-32 ----
  check_compact(32);
  __syncthreads();

  // ---- per-query merge of 4 columns (4x32 = 128 fixed) -> top-32 indices
  //      written straight to global mgG (u16 node index within batch) ----
  #pragma unroll 1
  for (int s = 0; s < 4; s++){
    int q = (wv << 2) + s;           // 0..63
    int qid = (b << 12) + qloc0 + q;
    unsigned e0 = buf[(lane & 31) * CSTR + (q << 2) + (lane >> 5)];
    unsigned e1 = buf[(lane & 31) * CSTR + (q << 2) + 2 + (lane >> 5)];
    unsigned T = 0;
    #pragma unroll 1
    for (int bb = 31; bb >= 0; --bb){
      unsigned cand = T | (1u << bb);
      int c = __popcll(__ballot(e0 < cand)) + __popcll(__ballot(e1 < cand));
      if (c <= 31) T = cand;
    }
    unsigned long long m0 = __ballot(e0 <= T);
    unsigned long long m1 = __ballot(e1 <= T);
    int b1 = __popcll(m0);
    unsigned long long ltm = (1ull << lane) - 1ull;
    int p0 = __popcll(m0 & ltm);
    int p1 = b1 + __popcll(m1 & ltm);
    if ((e0 <= T) && (p0 < 32)) mgG[qid * 32 + p0] = (unsigned short)(e0 & 0x3FFFu);
    if ((e1 <= T) && (p1 < 32)) mgG[qid * 32 + p1] = (unsigned short)(e1 & 0x3FFFu);
  }
}

// ---------------------------------------------------------------------------
// k_rerank: fp64 exact rerank + parallel rank-select. 2048 blocks x 256 thr,
// tiny LDS (~4.4 KB) -> many blocks/CU of TLP for the scattered x/lfr/pos
// loads (previously buried at 1-block/CU inside k_knn). 8 queries/block,
// 32 lanes per query, ONE candidate per lane. Rank-by-comparison (ties by
// mg position -- identical ordering to the old serial selection sort);
// lanes with rank<20 write nbr directly. No serial phase at all.
// ---------------------------------------------------------------------------
__global__ __launch_bounds__(256) void k_rerank(const float* __restrict__ x,
    const float* __restrict__ pos, const float* __restrict__ lfr,
    const unsigned short* __restrict__ mgG, int* __restrict__ nbr){
  __shared__ double qkf[8][68];
  int tid = threadIdx.x;
  int ql = tid >> 5;                 // query within block 0..7
  int j  = tid & 31;                 // candidate slot 0..31 (mg position)
  int qid = blockIdx.x * 8 + ql;     // 0..16383
  int b = qid >> 12;
  int bbase = b << 14;
  int node_q = bbase + ((qid & 4095) << 2);

  // build qkf cooperatively (32 lanes per query; same formulas as before)
  {
    const float* xr = x + node_q * 64;
    for (int dd = j; dd < 67; dd += 32){
      double val;
      if (dd < 16) val = (double)xr[dd];
      else if (dd < 64){
        int r = dd - 16; int k = r / 3; int a = r - 3 * k;
        val = (double)lfr[node_q*9 + a]     * (double)xr[16 + 3*k]
            + (double)lfr[node_q*9 + 3 + a] * (double)xr[17 + 3*k]
            + (double)lfr[node_q*9 + 6 + a] * (double)xr[18 + 3*k];
      } else val = (double)pos[node_q*3 + (dd - 64)];
      qkf[ql][dd] = val;
    }
  }
  __syncthreads();

  // rerank candidate j (identical summation order to the previous kernel)
  int idx = (int)mgG[qid * 32 + j];
  int node = bbase + idx;
  const float* xr = x + node * 64;
  double R[9];
  #pragma unroll
  for (int t = 0; t < 9; t++) R[t] = (double)lfr[node * 9 + t];
  double d2 = 0.0;
  #pragma unroll
  for (int dd = 0; dd < 16; dd++){ double t = (double)xr[dd] - qkf[ql][dd]; d2 += t * t; }
  #pragma unroll
  for (int k = 0; k < 16; k++){
    double v0 = xr[16 + 3*k], v1 = xr[17 + 3*k], v2 = xr[18 + 3*k];
    #pragma unroll
    for (int a = 0; a < 3; a++){
      double val = R[a] * v0 + R[3 + a] * v1 + R[6 + a] * v2;
      double t = val - qkf[ql][16 + 3*k + a]; d2 += t * t;
    }
  }
  #pragma unroll
  for (int a = 0; a < 3; a++){ double t = (double)pos[node*3 + a] - qkf[ql][64 + a]; d2 += t * t; }

  // rank within the query's 32 lanes: (d2, j) lexicographic == old sort order
  int base = (tid & 32) ? 32 : 0;    // half-wave base within the wave
  int rank = 0;
  #pragma unroll 1
  for (int j2 = 0; j2 < 32; j2++){
    double o = __shfl(d2, base + j2, 64);
    rank += (o < d2) || ((o == d2) && (j2 < j));
  }
  if (rank < KNN) nbr[qid * KNN + rank] = node;
}

// ---------------------------------------------------------------------------
// k_mlp: 8 queries/block = 160 edge-rows (10 m-tiles), 512 thr. bf16 MFMA
// both layers, fp32 acc. Weights pre-converted by k_wprep; staged as
// 8 uint4 copies/thread at kernel start (overlapped with init loads).
// ---------------------------------------------------------------------------
#define M_X   0         // xs f32[160][68] = 43520 ; later a1B bf16[4][160][32] = 40960
#define M_H   43520     // hB bf16[4][160][32] = 40960
#define M_W1  84480     // wt1 bf16[4][128][32] = 32768
#define M_W2  117248    // wt2 bf16[4][128][32] = 32768
#define M_B1  150016    // b1 f32[128]
#define M_B2  150528    // b2 f32[128]
#define M_NBR 151040    // nbrL i32[160] = 640
#define M_XD  151680    // xdL f32[8][64] = 2048
#define M_LF  153728    // lfL f32[8][9] = 288
#define M_SZ  154048

__global__ __launch_bounds__(512) void k_mlp(const float* __restrict__ x,
    const float* __restrict__ lfr, const int* __restrict__ nbr,
    const unsigned short* __restrict__ wb1, const unsigned short* __restrict__ wb2,
    const float* __restrict__ b1, const float* __restrict__ b2,
    float* __restrict__ out){
  __shared__ __attribute__((aligned(16))) char smem[M_SZ];
  float* xsF = (float*)(smem + M_X);
  unsigned short* a1B = (unsigned short*)(smem + M_X);   // overlays xs (dead)
  unsigned short* hB = (unsigned short*)(smem + M_H);
  unsigned short* wt1 = (unsigned short*)(smem + M_W1);
  unsigned short* wt2 = (unsigned short*)(smem + M_W2);
  float* b1L = (float*)(smem + M_B1);
  float* b2L = (float*)(smem + M_B2);
  int*   nbrL = (int*)(smem + M_NBR);
  float* xdL  = (float*)(smem + M_XD);
  float* lfL  = (float*)(smem + M_LF);

  int tid = threadIdx.x;
  int qid0 = blockIdx.x * 8;
  int lane = tid & 63, wv = tid >> 6;
  int l15 = lane & 15, quad = lane >> 4;

  // ---- init loads: weights (uint4 copies) + nbr/xd/lf/biases, one barrier ----
  {
    const uint4* g1 = (const uint4*)wb1;
    const uint4* g2 = (const uint4*)wb2;
    uint4* l1 = (uint4*)wt1;
    uint4* l2 = (uint4*)wt2;
    #pragma unroll
    for (int p = 0; p < 4; p++){
      l1[tid + (p << 9)] = g1[tid + (p << 9)];
      l2[tid + (p << 9)] = g2[tid + (p << 9)];
    }
  }
  if (tid < 160) nbrL[tid] = nbr[qid0 * 20 + tid];
  {
    int q = tid >> 6, d = tid & 63;
    int qid = qid0 + q;
    int node = ((qid >> 12) << 14) + ((qid & 4095) << 2);
    xdL[q * 64 + d] = x[node * 64 + d];
  }
  if (tid < 72){
    int q = tid / 9, j = tid - 9 * q;
    int qid = qid0 + q;
    int node = ((qid >> 12) << 14) + ((qid & 4095) << 2);
    lfL[q * 9 + j] = lfr[node * 9 + j];
  }
  if (tid < 128){ b1L[tid] = b1[tid]; b2L[tid] = b2[tid]; }
  __syncthreads();

  // ---- gather x_src into xs (160 rows x 64 f32, stride 68) ----
  {
    int f4 = tid & 15;
    #pragma unroll
    for (int p = 0; p < 5; p++){
      int e = (tid >> 4) + (p << 5);
      float4 v = *(const float4*)&x[(size_t)nbrL[e] * 64 + (f4 << 2)];
      *(float4*)&xsF[e * 68 + (f4 << 2)] = v;
    }
  }
  __syncthreads();

  // ---- build h bf16 into hB [d>>5][e][d&31] ----
  {
    int d = tid & 127, eo = tid >> 7;   // eo 0..3
    int cls, kk = 0, aa = 0;
    if (d < 64) cls = 0;
    else { int dd = d - 64;
      if (dd < 16) cls = 1;
      else { cls = 2; int r = dd - 16; kk = (r * 21846) >> 16; aa = r - 3 * kk; } }
    int hoff = ((d >> 5) * 160) * 32 + (d & 31);
    #pragma unroll 4
    for (int p = 0; p < 40; p++){
      int e = eo + (p << 2);
      int q = (e * 3277) >> 16;       // e/20 for e<160
      float v;
      if (cls == 0) v = xdL[q * 64 + d];
      else if (cls == 1) v = xsF[e * 68 + (d - 64)] - xdL[q * 64 + (d - 64)];
      else {
        int base = 16 + 3 * kk;
        float u0 = xsF[e * 68 + base]     - xdL[q * 64 + base];
        float u1 = xsF[e * 68 + base + 1] - xdL[q * 64 + base + 1];
        float u2 = xsF[e * 68 + base + 2] - xdL[q * 64 + base + 2];
        v = lfL[q * 9 + aa * 3] * u0 + lfL[q * 9 + aa * 3 + 1] * u1 + lfL[q * 9 + aa * 3 + 2] * u2;
      }
      hB[hoff + e * 32] = f2bf_rne(v);
    }
  }
  __syncthreads();   // hB done; xs dead (a1B may now be written)

  // ---- layer 1: a1 = relu(h @ W1 + b1) ----
  {
    s16x8 bfr[4];
    #pragma unroll
    for (int ks = 0; ks < 4; ks++)
      bfr[ks] = *(const s16x8*)(wt1 + ((ks * 128 + (wv << 4) + l15) * 32 + (quad << 3)));
    float b1v = b1L[(wv << 4) + l15];
    int colhi = wv >> 1, collo = ((wv & 1) << 4) + l15;
    #pragma unroll
    for (int mt = 0; mt < 10; mt++){
      f32x4 acc = (f32x4){0.f, 0.f, 0.f, 0.f};
      #pragma unroll
      for (int ks = 0; ks < 4; ks++){
        s16x8 af = *(const s16x8*)(hB + ((ks * 160 + (mt << 4) + l15) * 32 + (quad << 3)));
        acc = __builtin_amdgcn_mfma_f32_16x16x32_bf16(af, bfr[ks], acc, 0, 0, 0);
      }
      #pragma unroll
      for (int r = 0; r < 4; r++){
        float v = fmaxf(acc[r] + b1v, 0.f);
        int row = (mt << 4) + (quad << 2) + r;
        a1B[(colhi * 160 + row) * 32 + collo] = f2bf_rne(v);
      }
    }
  }
  __syncthreads();   // a1 complete

  // ---- layer 2 + max over edges (registers only) ----
  {
    s16x8 bfr[4];
    #pragma unroll
    for (int ks = 0; ks < 4; ks++)
      bfr[ks] = *(const s16x8*)(wt2 + ((ks * 128 + (wv << 4) + l15) * 32 + (quad << 3)));
    float mxv[8];
    #pragma unroll
    for (int q = 0; q < 8; q++) mxv[q] = -3.0e38f;
    const int QA[10]  = {0,0,1,2,3,4,4,5,6,7};
    const int CUT[10] = {16,4,8,12,16,16,4,8,12,16};
    #pragma unroll
    for (int mt = 0; mt < 10; mt++){
      f32x4 acc = (f32x4){0.f, 0.f, 0.f, 0.f};
      #pragma unroll
      for (int ks = 0; ks < 4; ks++){
        s16x8 af = *(const s16x8*)(a1B + ((ks * 160 + (mt << 4) + l15) * 32 + (quad << 3)));
        acc = __builtin_amdgcn_mfma_f32_16x16x32_bf16(af, bfr[ks], acc, 0, 0, 0);
      }
      int qa = QA[mt], cut = CUT[mt];
      if (cut >= 16){
        #pragma unroll
        for (int r = 0; r < 4; r++) mxv[qa] = fmaxf(mxv[qa], acc[r]);
      } else {
        #pragma unroll
        for (int r = 0; r < 4; r++){
          int lr = (quad << 2) + r;
          bool toA = lr < cut;
          mxv[qa]     = fmaxf(mxv[qa],     toA ? acc[r] : -3.0e38f);
          mxv[qa + 1] = fmaxf(mxv[qa + 1], toA ? -3.0e38f : acc[r]);
        }
      }
    }
    // combine across quads (rows) -- all lanes end with full per-col max
    #pragma unroll
    for (int q = 0; q < 8; q++){
      float v = mxv[q];
      v = fmaxf(v, __shfl_xor(v, 16, 64));
      v = fmaxf(v, __shfl_xor(v, 32, 64));
      mxv[q] = v;
    }
    if (quad == 0){
      int col = (wv << 4) + l15;
      float b2v = b2L[col];
      #pragma unroll
      for (int q = 0; q < 8; q++)
        out[(size_t)(qid0 + q) * 128 + col] = mxv[q] + b2v;
    }
  }
}

// ---------------------------------------------------------------------------
// k_tail: pos[idx], batch[idx], lframes[idx] as fp32 at flat offsets.
// ---------------------------------------------------------------------------
__global__ __launch_bounds__(256) void k_tail(const float* __restrict__ pos,
    const float* __restrict__ lfr, float* __restrict__ out){
  int q = blockIdx.x * 256 + threadIdx.x;   // 0..16383
  int b = q >> 12;
  int node = (b << 14) + ((q & 4095) << 2);
  float* o_pos = out + 2097152;    // 16384*128
  float* o_bat = out + 2146304;    // + 16384*3
  float* o_lf  = out + 2162688;    // + 16384
  #pragma unroll
  for (int j = 0; j < 3; j++) o_pos[q * 3 + j] = pos[node * 3 + j];
  o_bat[q] = (float)b;
  #pragma unroll
  for (int j = 0; j < 9; j++) o_lf[q * 9 + j] = lfr[node * 9 + j];
}

extern "C" void kernel_launch(void* const* d_in, const int* in_sizes, int n_in,
                              void* d_out, int out_size, void* d_ws, size_t ws_size,
                              hipStream_t stream){
  const float* x   = (const float*)d_in[0];
  const float* pos = (const float*)d_in[1];
  const float* lfr = (const float*)d_in[2];
  // d_in[3] = batch (recomputed analytically)
  const float* W1  = (const float*)d_in[4];
  const float* b1  = (const float*)d_in[5];
  const float* W2  = (const float*)d_in[6];
  const float* b2  = (const float*)d_in[7];

  unsigned short* kfB = (unsigned short*)d_ws;
  float* normB = (float*)((char*)d_ws + WS_NORM);
  int*   nbr   = (int*)((char*)d_ws + WS_NBR);
  unsigned short* wb1 = (unsigned short*)((char*)d_ws + WS_WT1);
  unsigned short* wb2 = (unsigned short*)((char*)d_ws + WS_WT2);
  unsigned short* mgG = (unsigned short*)((char*)d_ws + WS_MG);
  float* out = (float*)d_out;

  hipLaunchKernelGGL(k_prep,   dim3(256),  dim3(256),  0, stream, x, pos, lfr, kfB, normB);
  hipLaunchKernelGGL(k_wprep,  dim3(64),   dim3(256),  0, stream, W1, W2, wb1, wb2);
  hipLaunchKernelGGL(k_knn,    dim3(256),  dim3(1024), 0, stream, kfB, normB, mgG);
  hipLaunchKernelGGL(k_rerank, dim3(2048), dim3(256),  0, stream, x, pos, lfr, mgG, nbr);
  hipLaunchKernelGGL(k_mlp,    dim3(2048), dim3(512),  0, stream, x, lfr, nbr, wb1, wb2, b1, b2, out);
  hipLaunchKernelGGL(k_tail,   dim3(64),   dim3(256),  0, stream, pos, lfr, out);
}

// Round 13
// 535.643 us; speedup vs baseline: 1.8768x; 1.1152x over previous
//
#include <hip/hip_runtime.h>
#include <hip/hip_bf16.h>

// Problem constants
#define NTOT 65536      // B*N
#define KNN  20
#define KROW 104        // bf16 kf row stride (67 dims + pad)

typedef __attribute__((ext_vector_type(4))) float f32x4;
typedef __attribute__((ext_vector_type(8))) short s16x8;

// ws layout (bytes): kfB bf16[65536][104] | normB f32[65536] | nbr i32[16384*20]
//                  | wb1 bf16[16384] | wb2 bf16[16384] | mg u16[16384*32]
#define WS_NORM 13631488
#define WS_NBR  13893632
#define WS_WT1  15204352
#define WS_WT2  15237120
#define WS_MG   15269888    // 1 MB; ws end = 16318464 < 16 MiB

// ---- k_knn LDS map (bytes) ----
// buf: 144 rows x 257 dwords (256 columns + 1 pad for bank spread) = 148032
// col = qLocal*4 + kq   (qLocal 0..63 within block, kq = key quarter 0..3)
#define ROWS 144
#define CSTR 257
#define OFF_TAUG 149056     // unsigned tauG[64]
#define KNN_SMEM 149312
#define THRESH 64           // compact a column when cnt > THRESH (max cn ~104+ <= 144)

__device__ __forceinline__ unsigned short f2bf_rne(float v){
  unsigned u = __float_as_uint(v);
  return (unsigned short)((u + 0x7FFFu + ((u >> 16) & 1u)) >> 16);
}

// ---------------------------------------------------------------------------
// k_prep: kf = [s(16), R^T v(48), pos(3)] -> bf16 rows (stride 104) + f32 norm
// ---------------------------------------------------------------------------
__global__ __launch_bounds__(256) void k_prep(const float* __restrict__ x,
        const float* __restrict__ pos, const float* __restrict__ lfr,
        unsigned short* __restrict__ kfB, float* __restrict__ normB){
  int n = blockIdx.x * 256 + threadIdx.x;
  const float* xr = x + n * 64;
  float R[9];
  #pragma unroll
  for (int j = 0; j < 9; j++) R[j] = lfr[n * 9 + j];
  float c[67];
  #pragma unroll
  for (int i = 0; i < 16; i++) c[i] = xr[i];
  #pragma unroll
  for (int k = 0; k < 16; k++){
    float v0 = xr[16 + 3*k], v1 = xr[17 + 3*k], v2 = xr[18 + 3*k];
    #pragma unroll
    for (int a = 0; a < 3; a++)
      c[16 + 3*k + a] = R[a] * v0 + R[3 + a] * v1 + R[6 + a] * v2;  // R^T v
  }
  #pragma unroll
  for (int a = 0; a < 3; a++) c[64 + a] = pos[n * 3 + a];
  float sq = 0.f;
  #pragma unroll
  for (int d = 0; d < 67; d++) sq += c[d] * c[d];
  __attribute__((aligned(16))) unsigned short row[KROW];
  #pragma unroll
  for (int d = 0; d < 67; d++) row[d] = f2bf_rne(c[d]);
  #pragma unroll
  for (int d = 67; d < KROW; d++) row[d] = 0;
  uint4* dst = (uint4*)(kfB + (size_t)n * KROW);
  const uint4* s4 = (const uint4*)row;
  #pragma unroll
  for (int i = 0; i < 13; i++) dst[i] = s4[i];
  normB[n] = sq;
}

// ---------------------------------------------------------------------------
// k_wprep: pre-convert W1/W2 (f32, row-major [128][128]) to bf16 in the
// MFMA fragment layout a = ((k>>5)*128 + n)*32 + (k&31). Coalesced writes.
// ---------------------------------------------------------------------------
__global__ __launch_bounds__(256) void k_wprep(const float* __restrict__ W1,
        const float* __restrict__ W2, unsigned short* __restrict__ wb1,
        unsigned short* __restrict__ wb2){
  int a = blockIdx.x * 256 + threadIdx.x;      // 0..16383
  int kb = a >> 12, n = (a >> 5) & 127, kl = a & 31;
  int i = ((kb << 5) + kl) * 128 + n;
  wb1[a] = f2bf_rne(W1[i]);
  wb2[a] = f2bf_rne(W2[i]);
}

// ---------------------------------------------------------------------------
// col_compact32: EXACT top-32 (full 32-bit packed) of one column, cn<=144.
// Used only for the final per-column compact (merge expects exactly 32).
// ---------------------------------------------------------------------------
__device__ __forceinline__ unsigned col_compact32(unsigned* buf,
    int col, int cn, int lane){
  unsigned e0 = (lane < cn) ? buf[lane * CSTR + col] : 0xFFFFFFFFu;
  unsigned e1 = (lane + 64 < cn) ? buf[(lane + 64) * CSTR + col] : 0xFFFFFFFFu;
  unsigned T = 0;
  #pragma unroll 1
  for (int b = 31; b >= 0; --b){
    unsigned cand = T | (1u << b);
    int c = __popcll(__ballot(e0 < cand)) + __popcll(__ballot(e1 < cand));
    if (c <= 31) T = cand;   // largest U with count(<U)<=31  ==> 32nd smallest
  }
  unsigned long long m0 = __ballot(e0 <= T);
  unsigned long long m1 = __ballot(e1 <= T);
  int b1 = __popcll(m0);
  unsigned long long ltm = (1ull << lane) - 1ull;
  if (e0 <= T) buf[__popcll(m0 & ltm) * CSTR + col] = e0;
  if (e1 <= T) buf[(b1 + __popcll(m1 & ltm)) * CSTR + col] = e1;
  return T;
}

// ---------------------------------------------------------------------------
// col_compact18: mid-scan compact at d2 granularity (bits 31..14 only).
// Keeps (e>>14) <= (T>>14): tie-inclusive SUPERSET of the exact top-32
// (T+2^14 > exact 32nd value), count kc in [32, 32+ties]. 18 ballot rounds
// instead of 32. Returns T | kc (T's low 14 bits are zero by construction).
// ---------------------------------------------------------------------------
__device__ __forceinline__ unsigned col_compact18(unsigned* buf,
    int col, int cn, int lane){
  unsigned e0 = (lane < cn) ? buf[lane * CSTR + col] : 0xFFFFFFFFu;
  unsigned e1 = (lane + 64 < cn) ? buf[(lane + 64) * CSTR + col] : 0xFFFFFFFFu;
  unsigned T = 0;
  #pragma unroll 1
  for (int b = 31; b >= 14; --b){
    unsigned cand = T | (1u << b);
    int c = __popcll(__ballot(e0 < cand)) + __popcll(__ballot(e1 < cand));
    if (c <= 31) T = cand;   // largest mult-of-2^14 with count(<T)<=31
  }
  unsigned th = T >> 14;
  unsigned long long m0 = __ballot((e0 >> 14) <= th);
  unsigned long long m1 = __ballot((e1 >> 14) <= th);
  int b1 = __popcll(m0);
  int kc = b1 + __popcll(m1);
  unsigned long long ltm = (1ull << lane) - 1ull;
  if ((e0 >> 14) <= th) buf[__popcll(m0 & ltm) * CSTR + col] = e0;
  if ((e1 >> 14) <= th) buf[(b1 + __popcll(m1 & ltm)) * CSTR + col] = e1;
  return T | (unsigned)kc;
}

// ---------------------------------------------------------------------------
// k_knn: R3 scan structure, epilogue split out (R12). Barrier-free
// wave-autonomous scan, 256 blocks x 1024 thr (16 waves). Wave (wq,kq): 16
// queries x 4096 keys. Keys direct from global (L2-resident). Counts in
// quad-uniform registers; shared monotone tau via atomicMin, refreshed every
// 4 groups. NEW: mid-scan compaction uses the 18-round d2-granular select
// (tie-inclusive superset, tracked count) -- ~45% fewer compact VALU insts.
// ---------------------------------------------------------------------------
__global__ __launch_bounds__(1024, 4) void k_knn(
    const unsigned short* __restrict__ kfB, const float* __restrict__ normB,
    unsigned short* __restrict__ mgG){
  __shared__ __attribute__((aligned(16))) char smem[KNN_SMEM];
  unsigned* buf = (unsigned*)smem;
  unsigned* tauG = (unsigned*)(smem + OFF_TAUG);

  int tid = threadIdx.x;
  int blk = blockIdx.x;
  int b = blk & 3;                 // batch; XCD (blk%8) serves one batch slice
  int qloc0 = (blk >> 2) << 6;     // query block within batch: 0..4032
  int bbase = b << 14;

  if (tid < 64) tauG[tid] = 0x7F7FC000u;   // huge float (not NaN)

  int lane = tid & 63;
  int wv = tid >> 6;               // 0..15
  int wq = wv >> 2;                // query sub-group 0..3
  int kq = wv & 3;                 // key quarter 0..3
  int l15 = lane & 15, quad = lane >> 4;
  int colB = (wq << 6) + kq;       // col = colB + quad*16 + r*4

  // A fragments: wave's 16 queries
  int qloc = qloc0 + (wq << 4);
  s16x8 af[3];
  {
    int nodeA = bbase + ((qloc + l15) << 2);
    const unsigned short* ap = kfB + (size_t)nodeA * KROW + quad * 8;
    af[0] = *(const s16x8*)(ap);
    af[1] = *(const s16x8*)(ap + 32);
    af[2] = *(const s16x8*)(ap + 64);
  }
  float qsq[4];
  #pragma unroll
  for (int r = 0; r < 4; r++)
    qsq[r] = normB[bbase + ((qloc + (quad << 2) + r) << 2)];

  float tauR[4] = {3.0e38f, 3.0e38f, 3.0e38f, 3.0e38f};
  int cntR[4];                     // quad-uniform per-column counts (registers)

  // key stream pointers (lane l15 -> key (kq*4096 + g*16 + l15))
  const unsigned short* kp = kfB + (size_t)(bbase + (kq << 12) + l15) * KROW + quad * 8;
  const float* np = normB + (bbase + (kq << 12) + l15);

  __syncthreads();   // tauG init visible

  s16x8 cK[4][3];
  float nK[4];
  #define LOADK(S) do { \
      cK[S][0] = *(const s16x8*)(kp); \
      cK[S][1] = *(const s16x8*)(kp + 32); \
      cK[S][2] = *(const s16x8*)(kp + 64); \
      nK[S] = *np; kp += 16 * KROW; np += 16; } while (0)

  auto comp = [&](const s16x8 bf[3], float ksqv, float d2v[4]){
    f32x4 acc = (f32x4){0.f, 0.f, 0.f, 0.f};
    acc = __builtin_amdgcn_mfma_f32_16x16x32_bf16(af[0], bf[0], acc, 0, 0, 0);
    acc = __builtin_amdgcn_mfma_f32_16x16x32_bf16(af[1], bf[1], acc, 0, 0, 0);
    acc = __builtin_amdgcn_mfma_f32_16x16x32_bf16(af[2], bf[2], acc, 0, 0, 0);
    #pragma unroll
    for (int r = 0; r < 4; r++)
      d2v[r] = fmaxf(qsq[r] + ksqv - 2.f * acc[r], 0.f);
  };

  auto seed = [&](const float d2v[4], int g){
    int kidx = (kq << 12) + (g << 4) + l15;
    #pragma unroll
    for (int r = 0; r < 4; r++){
      unsigned pk = ((__float_as_uint(d2v[r]) + 0x2000u) & 0xFFFFC000u) | (unsigned)kidx;
      buf[((g << 4) + l15) * CSTR + colB + (quad << 4) + (r << 2)] = pk;
    }
  };

  auto process = [&](const float d2v[4], int g){
    bool p[4];
    #pragma unroll
    for (int r = 0; r < 4; r++) p[r] = d2v[r] < tauR[r];
    if (__any(p[0] | p[1] | p[2] | p[3])){
      int kidx = (kq << 12) + (g << 4) + l15;
      #pragma unroll
      for (int r = 0; r < 4; r++){
        unsigned long long m = __ballot(p[r]);
        if (m){
          int lo = (int)((m >> (quad << 4)) & 0xFFFFull);
          if (lo){
            int colr = colB + (quad << 4) + (r << 2);
            int pre = __popc(lo & ((1 << l15) - 1));
            if (p[r]){
              unsigned pk = ((__float_as_uint(d2v[r]) + 0x2000u) & 0xFFFFC000u) | (unsigned)kidx;
              buf[(cntR[r] + pre) * CSTR + colr] = pk;
            }
            cntR[r] += __popc(lo);      // quad-uniform update, no atomics
          }
        }
      }
    }
  };

  // mid-scan compact (18-round, tie-inclusive, tracked count) + tau update
  auto check_compact = [&](int limit){
    #pragma unroll
    for (int r = 0; r < 4; r++){
      unsigned long long mr = __ballot(cntR[r] > limit);
      while (mr){
        int ldr = __ffsll((unsigned long long)mr) - 1;
        int qd = ldr >> 4;
        mr &= ~(0xFFFFull << (qd << 4));
        int col = colB + (qd << 4) + (r << 2);
        int cn = __shfl(cntR[r], qd << 4, 64);
        unsigned Tk = col_compact18(buf, col, cn, lane);
        if (quad == qd) cntR[r] = (int)(Tk & 0x3FFFu);
        if (lane == 0) atomicMin(&tauG[(wq << 4) + (qd << 2) + r], Tk & 0xFFFFC000u);
      }
    }
  };

  // ---- prologue: fill 4 slots, seed groups 0..3 unconditionally ----
  float d2v[4];
  LOADK(0); LOADK(1); LOADK(2); LOADK(3);    // g0..g3
  #pragma unroll
  for (int j = 0; j < 4; j++){
    comp(cK[j], nK[j], d2v);
    seed(d2v, j);
    LOADK(j);                                 // prefetch g4..g7
  }
  #pragma unroll
  for (int r = 0; r < 4; r++) cntR[r] = 64;

  // ---- main scan: 4 groups/iter, 4-deep register prefetch ----
  #pragma unroll 1
  for (int g = 4; g < 256; g += 4){
    #pragma unroll
    for (int j = 0; j < 4; j++){
      comp(cK[j], nK[j], d2v);
      LOADK(j);                               // prefetch g+4+j (tail overrun reads valid ws bytes)
      process(d2v, g + j);
    }
    check_compact(THRESH);
    uint4 tg = *(const uint4*)&tauG[(wq << 4) + (quad << 2)];
    tauR[0] = __uint_as_float(tg.x & 0xFFFFC000u);
    tauR[1] = __uint_as_float(tg.y & 0xFFFFC000u);
    tauR[2] = __uint_as_float(tg.z & 0xFFFFC000u);
    tauR[3] = __uint_as_float(tg.w & 0xFFFFC000u);
  }

  // ---- final per-column EXACT top-32 (merge expects exactly 32 rows) ----
  {
    #pragma unroll
    for (int r = 0; r < 4; r++){
      unsigned long long mr = __ballot(cntR[r] > 32);
      while (mr){
        int ldr = __ffsll((unsigned long long)mr) - 1;
        int qd = ldr >> 4;
        mr &= ~(0xFFFFull << (qd << 4));
        int col = colB + (qd << 4) + (r << 2);
        int cn = __shfl(cntR[r], qd << 4, 64);
        col_compact32(buf, col, cn, lane);
        if (quad == qd) cntR[r] = 32;
      }
    }
  }
  __syncthreads();

  // ---- per-query merge of 4 columns (4x32 = 128 fixed) -> top-32 indices
  //      written straight to global mgG (u16 node index within batch) ----
  #pragma unroll 1
  for (int s = 0; s < 4; s++){
    int q = (wv << 2) + s;           // 0..63
    int qid = (b << 12) + qloc0 + q;
    unsigned e0 = buf[(lane & 31) * CSTR + (q << 2) + (lane >> 5)];
    unsigned e1 = buf[(lane & 31) * CSTR + (q << 2) + 2 + (lane >> 5)];
    unsigned T = 0;
    #pragma unroll 1
    for (int bb = 31; bb >= 0; --bb){
      unsigned cand = T | (1u << bb);
      int c = __popcll(__ballot(e0 < cand)) + __popcll(__ballot(e1 < cand));
      if (c <= 31) T = cand;
    }
    unsigned long long m0 = __ballot(e0 <= T);
    unsigned long long m1 = __ballot(e1 <= T);
    int b1 = __popcll(m0);
    unsigned long long ltm = (1ull << lane) - 1ull;
    int p0 = __popcll(m0 & ltm);
    int p1 = b1 + __popcll(m1 & ltm);
    if ((e0 <= T) && (p0 < 32)) mgG[qid * 32 + p0] = (unsigned short)(e0 & 0x3FFFu);
    if ((e1 <= T) && (p1 < 32)) mgG[qid * 32 + p1] = (unsigned short)(e1 & 0x3FFFu);
  }
}

// ---------------------------------------------------------------------------
// k_rerank: fp64 exact rerank + parallel rank-select. 2048 blocks x 256 thr,
// tiny LDS -> many blocks/CU of TLP for the scattered x/lfr/pos loads.
// 8 queries/block, 32 lanes per query, ONE candidate per lane. Ranking ties
// by mg position == the original serial selection-sort order.
// ---------------------------------------------------------------------------
__global__ __launch_bounds__(256) void k_rerank(const float* __restrict__ x,
    const float* __restrict__ pos, const float* __restrict__ lfr,
    const unsigned short* __restrict__ mgG, int* __restrict__ nbr){
  __shared__ double qkf[8][68];
  int tid = threadIdx.x;
  int ql = tid >> 5;                 // query within block 0..7
  int j  = tid & 31;                 // candidate slot 0..31 (mg position)
  int qid = blockIdx.x * 8 + ql;     // 0..16383
  int b = qid >> 12;
  int bbase = b << 14;
  int node_q = bbase + ((qid & 4095) << 2);

  // build qkf cooperatively (32 lanes per query; same formulas as before)
  {
    const float* xr = x + node_q * 64;
    for (int dd = j; dd < 67; dd += 32){
      double val;
      if (dd < 16) val = (double)xr[dd];
      else if (dd < 64){
        int r = dd - 16; int k = r / 3; int a = r - 3 * k;
        val = (double)lfr[node_q*9 + a]     * (double)xr[16 + 3*k]
            + (double)lfr[node_q*9 + 3 + a] * (double)xr[17 + 3*k]
            + (double)lfr[node_q*9 + 6 + a] * (double)xr[18 + 3*k];
      } else val = (double)pos[node_q*3 + (dd - 64)];
      qkf[ql][dd] = val;
    }
  }
  __syncthreads();

  // rerank candidate j (identical summation order to the previous kernel)
  int idx = (int)mgG[qid * 32 + j];
  int node = bbase + idx;
  const float* xr = x + node * 64;
  double R[9];
  #pragma unroll
  for (int t = 0; t < 9; t++) R[t] = (double)lfr[node * 9 + t];
  double d2 = 0.0;
  #pragma unroll
  for (int dd = 0; dd < 16; dd++){ double t = (double)xr[dd] - qkf[ql][dd]; d2 += t * t; }
  #pragma unroll
  for (int k = 0; k < 16; k++){
    double v0 = xr[16 + 3*k], v1 = xr[17 + 3*k], v2 = xr[18 + 3*k];
    #pragma unroll
    for (int a = 0; a < 3; a++){
      double val = R[a] * v0 + R[3 + a] * v1 + R[6 + a] * v2;
      double t = val - qkf[ql][16 + 3*k + a]; d2 += t * t;
    }
  }
  #pragma unroll
  for (int a = 0; a < 3; a++){ double t = (double)pos[node*3 + a] - qkf[ql][64 + a]; d2 += t * t; }

  // rank within the query's 32 lanes: (d2, j) lexicographic == old sort order
  int base = (tid & 32) ? 32 : 0;    // half-wave base within the wave
  int rank = 0;
  #pragma unroll 1
  for (int j2 = 0; j2 < 32; j2++){
    double o = __shfl(d2, base + j2, 64);
    rank += (o < d2) || ((o == d2) && (j2 < j));
  }
  if (rank < KNN) nbr[qid * KNN + rank] = node;
}

// ---------------------------------------------------------------------------
// k_mlp: 8 queries/block = 160 edge-rows (10 m-tiles), 512 thr. bf16 MFMA
// both layers, fp32 acc. NEW: weight fragments loaded DIRECTLY from the
// pre-transposed wb1/wb2 (L2-resident) into registers -- no 64KB LDS staging,
// no per-block copies. LDS shrinks to ~88.5 KB.
// ---------------------------------------------------------------------------
#define M_X   0         // xs f32[160][68] = 43520 ; later a1B bf16[4][160][32] = 40960
#define M_H   43520     // hB bf16[4][160][32] = 40960
#define M_B1  84480     // b1 f32[128]
#define M_B2  84992     // b2 f32[128]
#define M_NBR 85504     // nbrL i32[160] = 640
#define M_XD  86144     // xdL f32[8][64] = 2048
#define M_LF  88192     // lfL f32[8][9] = 288
#define M_SZ  88512

__global__ __launch_bounds__(512) void k_mlp(const float* __restrict__ x,
    const float* __restrict__ lfr, const int* __restrict__ nbr,
    const unsigned short* __restrict__ wb1, const unsigned short* __restrict__ wb2,
    const float* __restrict__ b1, const float* __restrict__ b2,
    float* __restrict__ out){
  __shared__ __attribute__((aligned(16))) char smem[M_SZ];
  float* xsF = (float*)(smem + M_X);
  unsigned short* a1B = (unsigned short*)(smem + M_X);   // overlays xs (dead)
  unsigned short* hB = (unsigned short*)(smem + M_H);
  float* b1L = (float*)(smem + M_B1);
  float* b2L = (float*)(smem + M_B2);
  int*   nbrL = (int*)(smem + M_NBR);
  float* xdL  = (float*)(smem + M_XD);
  float* lfL  = (float*)(smem + M_LF);

  int tid = threadIdx.x;
  int qid0 = blockIdx.x * 8;
  int lane = tid & 63, wv = tid >> 6;
  int l15 = lane & 15, quad = lane >> 4;

  // ---- weight fragments: straight from global (L2) into registers ----
  s16x8 wf1[4], wf2[4];
  #pragma unroll
  for (int ks = 0; ks < 4; ks++){
    int a = (ks * 128 + (wv << 4) + l15) * 32 + (quad << 3);
    wf1[ks] = *(const s16x8*)(wb1 + a);
    wf2[ks] = *(const s16x8*)(wb2 + a);
  }

  // ---- init loads ----
  if (tid < 160) nbrL[tid] = nbr[qid0 * 20 + tid];
  {
    int q = tid >> 6, d = tid & 63;
    int qid = qid0 + q;
    int node = ((qid >> 12) << 14) + ((qid & 4095) << 2);
    xdL[q * 64 + d] = x[node * 64 + d];
  }
  if (tid < 72){
    int q = tid / 9, j = tid - 9 * q;
    int qid = qid0 + q;
    int node = ((qid >> 12) << 14) + ((qid & 4095) << 2);
    lfL[q * 9 + j] = lfr[node * 9 + j];
  }
  if (tid < 128){ b1L[tid] = b1[tid]; b2L[tid] = b2[tid]; }
  __syncthreads();

  // ---- gather x_src into xs (160 rows x 64 f32, stride 68) ----
  {
    int f4 = tid & 15;
    #pragma unroll
    for (int p = 0; p < 5; p++){
      int e = (tid >> 4) + (p << 5);
      float4 v = *(const float4*)&x[(size_t)nbrL[e] * 64 + (f4 << 2)];
      *(float4*)&xsF[e * 68 + (f4 << 2)] = v;
    }
  }
  __syncthreads();

  // ---- build h bf16 into hB [d>>5][e][d&31] ----
  {
    int d = tid & 127, eo = tid >> 7;   // eo 0..3
    int cls, kk = 0, aa = 0;
    if (d < 64) cls = 0;
    else { int dd = d - 64;
      if (dd < 16) cls = 1;
      else { cls = 2; int r = dd - 16; kk = (r * 21846) >> 16; aa = r - 3 * kk; } }
    int hoff = ((d >> 5) * 160) * 32 + (d & 31);
    #pragma unroll 4
    for (int p = 0; p < 40; p++){
      int e = eo + (p << 2);
      int q = (e * 3277) >> 16;       // e/20 for e<160
      float v;
      if (cls == 0) v = xdL[q * 64 + d];
      else if (cls == 1) v = xsF[e * 68 + (d - 64)] - xdL[q * 64 + (d - 64)];
      else {
        int base = 16 + 3 * kk;
        float u0 = xsF[e * 68 + base]     - xdL[q * 64 + base];
        float u1 = xsF[e * 68 + base + 1] - xdL[q * 64 + base + 1];
        float u2 = xsF[e * 68 + base + 2] - xdL[q * 64 + base + 2];
        v = lfL[q * 9 + aa * 3] * u0 + lfL[q * 9 + aa * 3 + 1] * u1 + lfL[q * 9 + aa * 3 + 2] * u2;
      }
      hB[hoff + e * 32] = f2bf_rne(v);
    }
  }
  __syncthreads();   // hB done; xs dead (a1B may now be written)

  // ---- layer 1: a1 = relu(h @ W1 + b1) ----
  {
    float b1v = b1L[(wv << 4) + l15];
    int colhi = wv >> 1, collo = ((wv & 1) << 4) + l15;
    #pragma unroll
    for (int mt = 0; mt < 10; mt++){
      f32x4 acc = (f32x4){0.f, 0.f, 0.f, 0.f};
      #pragma unroll
      for (int ks = 0; ks < 4; ks++){
        s16x8 af = *(const s16x8*)(hB + ((ks * 160 + (mt << 4) + l15) * 32 + (quad << 3)));
        acc = __builtin_amdgcn_mfma_f32_16x16x32_bf16(af, wf1[ks], acc, 0, 0, 0);
      }
      #pragma unroll
      for (int r = 0; r < 4; r++){
        float v = fmaxf(acc[r] + b1v, 0.f);
        int row = (mt << 4) + (quad << 2) + r;
        a1B[(colhi * 160 + row) * 32 + collo] = f2bf_rne(v);
      }
    }
  }
  __syncthreads();   // a1 complete

  // ---- layer 2 + max over edges (registers only) ----
  {
    float mxv[8];
    #pragma unroll
    for (int q = 0; q < 8; q++) mxv[q] = -3.0e38f;
    const int QA[10]  = {0,0,1,2,3,4,4,5,6,7};
    const int CUT[10] = {16,4,8,12,16,16,4,8,12,16};
    #pragma unroll
    for (int mt = 0; mt < 10; mt++){
      f32x4 acc = (f32x4){0.f, 0.f, 0.f, 0.f};
      #pragma unroll
      for (int ks = 0; ks < 4; ks++){
        s16x8 af = *(const s16x8*)(a1B + ((ks * 160 + (mt << 4) + l15) * 32 + (quad << 3)));
        acc = __builtin_amdgcn_mfma_f32_16x16x32_bf16(af, wf2[ks], acc, 0, 0, 0);
      }
      int qa = QA[mt], cut = CUT[mt];
      if (cut >= 16){
        #pragma unroll
        for (int r = 0; r < 4; r++) mxv[qa] = fmaxf(mxv[qa], acc[r]);
      } else {
        #pragma unroll
        for (int r = 0; r < 4; r++){
          int lr = (quad << 2) + r;
          bool toA = lr < cut;
          mxv[qa]     = fmaxf(mxv[qa],     toA ? acc[r] : -3.0e38f);
          mxv[qa + 1] = fmaxf(mxv[qa + 1], toA ? -3.0e38f : acc[r]);
        }
      }
    }
    // combine across quads (rows) -- all lanes end with full per-col max
    #pragma unroll
    for (int q = 0; q < 8; q++){
      float v = mxv[q];
      v = fmaxf(v, __shfl_xor(v, 16, 64));
      v = fmaxf(v, __shfl_xor(v, 32, 64));
      mxv[q] = v;
    }
    if (quad == 0){
      int col = (wv << 4) + l15;
      float b2v = b2L[col];
      #pragma unroll
      for (int q = 0; q < 8; q++)
        out[(size_t)(qid0 + q) * 128 + col] = mxv[q] + b2v;
    }
  }
}

// ---------------------------------------------------------------------------
// k_tail: pos[idx], batch[idx], lframes[idx] as fp32 at flat offsets.
// ---------------------------------------------------------------------------
__global__ __launch_bounds__(256) void k_tail(const float* __restrict__ pos,
    const float* __restrict__ lfr, float* __restrict__ out){
  int q = blockIdx.x * 256 + threadIdx.x;   // 0..16383
  int b = q >> 12;
  int node = (b << 14) + ((q & 4095) << 2);
  float* o_pos = out + 2097152;    // 16384*128
  float* o_bat = out + 2146304;    // + 16384*3
  float* o_lf  = out + 2162688;    // + 16384
  #pragma unroll
  for (int j = 0; j < 3; j++) o_pos[q * 3 + j] = pos[node * 3 + j];
  o_bat[q] = (float)b;
  #pragma unroll
  for (int j = 0; j < 9; j++) o_lf[q * 9 + j] = lfr[node * 9 + j];
}

extern "C" void kernel_launch(void* const* d_in, const int* in_sizes, int n_in,
                              void* d_out, int out_size, void* d_ws, size_t ws_size,
                              hipStream_t stream){
  const float* x   = (const float*)d_in[0];
  const float* pos = (const float*)d_in[1];
  const float* lfr = (const float*)d_in[2];
  // d_in[3] = batch (recomputed analytically)
  const float* W1  = (const float*)d_in[4];
  const float* b1  = (const float*)d_in[5];
  const float* W2  = (const float*)d_in[6];
  const float* b2  = (const float*)d_in[7];

  unsigned short* kfB = (unsigned short*)d_ws;
  float* normB = (float*)((char*)d_ws + WS_NORM);
  int*   nbr   = (int*)((char*)d_ws + WS_NBR);
  unsigned short* wb1 = (unsigned short*)((char*)d_ws + WS_WT1);
  unsigned short* wb2 = (unsigned short*)((char*)d_ws + WS_WT2);
  unsigned short* mgG = (unsigned short*)((char*)d_ws + WS_MG);
  float* out = (float*)d_out;

  hipLaunchKernelGGL(k_prep,   dim3(256),  dim3(256),  0, stream, x, pos, lfr, kfB, normB);
  hipLaunchKernelGGL(k_wprep,  dim3(64),   dim3(256),  0, stream, W1, W2, wb1, wb2);
  hipLaunchKernelGGL(k_knn,    dim3(256),  dim3(1024), 0, stream, kfB, normB, mgG);
  hipLaunchKernelGGL(k_rerank, dim3(2048), dim3(256),  0, stream, x, pos, lfr, mgG, nbr);
  hipLaunchKernelGGL(k_mlp,    dim3(2048), dim3(512),  0, stream, x, lfr, nbr, wb1, wb2, b1, b2, out);
  hipLaunchKernelGGL(k_tail,   dim3(64),   dim3(256),  0, stream, pos, lfr, out);
}